// Round 8
// baseline (922.347 us; speedup 1.0000x reference)
//
#include <hip/hip_runtime.h>

typedef __attribute__((ext_vector_type(8))) short short8;
typedef __attribute__((ext_vector_type(4))) int int4v;
typedef __attribute__((ext_vector_type(4))) float floatx4;
typedef __attribute__((ext_vector_type(4))) unsigned short ushort4v;

#define DEV __device__ __forceinline__

constexpr int M_TOT = 6272;   // 8 * 784 real output positions
constexpr int M_PAD = 6400;   // padded to 25*256 (pad rows read zeroed P slots)

DEV void async_ld16(const void* g, void* l) {
  __builtin_amdgcn_global_load_lds(
      (const __attribute__((address_space(1))) unsigned int*)g,
      (__attribute__((address_space(3))) unsigned int*)l,
      16, 0, 0);
}

DEV unsigned short f2bf(float x) {
  union { float f; unsigned int u; } v; v.f = x;
  unsigned int u = v.u;
  u += 0x7FFFu + ((u >> 16) & 1u);   // round-to-nearest-even
  return (unsigned short)(u >> 16);
}

DEV float bf2f(unsigned short s) {
  union { unsigned int u; float f; } v; v.u = ((unsigned int)s) << 16;
  return v.f;
}

// ---------------------------------------------------------------------------
// Weight transform: conv_w fp32 [O][C][3][3][3] -> bf16 [tap][o][c]  (B^T).
// ---------------------------------------------------------------------------
__global__ void wtrans(const float* __restrict__ w, unsigned short* __restrict__ wt,
                       int total /* = O*C, multiple of 256 */) {
  __shared__ unsigned short l[256 * 27];
  const int tid  = threadIdx.x;
  const int base = blockIdx.x * 256;
  #pragma unroll 1
  for (int j = tid; j < 256 * 27; j += 256)
    l[j] = f2bf(w[(size_t)base * 27 + j]);
  __syncthreads();
  #pragma unroll 1
  for (int tap = 0; tap < 27; ++tap)
    wt[(size_t)tap * total + base + tid] = l[tid * 27 + tap];
}

// ---------------------------------------------------------------------------
// Build P1: videos fp32 [8][1024][14][14] -> P1 bf16 [t=8][s=6][16][16][1024]
// P1[t][s][h+1][w+1][c] = videos[t-5+s][c][h][w] for s in 1..4 (else zero).
// ---------------------------------------------------------------------------
__global__ void build_P1(const float* __restrict__ videos, unsigned short* __restrict__ P1) {
  const int f  = blockIdx.x;
  const int c0 = blockIdx.y * 64;
  const int tid = threadIdx.x;
  __shared__ unsigned short tile[64][196];

  #pragma unroll 1
  for (int it = 0; it < 49; ++it) {       // 49*256 = 64*196 exactly
    int idx = it * 256 + tid;
    int c = idx / 196, r = idx - c * 196;
    tile[c][r] = f2bf(videos[(size_t)(f * 1024 + c0 + c) * 196 + r]);
  }
  __syncthreads();

  const int c   = tid & 63;
  const int hwq = tid >> 6;
  #pragma unroll 1
  for (int s = 1; s <= 4; ++s) {
    int t = f + 5 - s;
    if (t > 7) continue;
    unsigned short* dst = P1 + (size_t)(t * 6 + s) * 256 * 1024 + (size_t)c0;
    #pragma unroll 1
    for (int it = 0; it < 49; ++it) {
      int hw = it * 4 + hwq;
      int h = hw / 14, w = hw - h * 14;
      dst[(size_t)((h + 1) * 16 + (w + 1)) * 1024 + c] = tile[c][hw];
    }
  }
}

// Pinned-order LDS read / global load (issue order = program order).
#define DSR(dst, addr, off) \
  asm volatile("ds_read_b128 %0, %1 offset:" #off : "=&v"(dst) : "v"(addr))
#define GLB(dst, p) \
  asm volatile("global_load_dwordx4 %0, %1, off" : "=&v"(dst) : "v"(p))
#define WAITL(n) \
  asm volatile("s_waitcnt lgkmcnt(" #n ")" ::: "memory"); \
  __builtin_amdgcn_sched_barrier(0)
#define SB0 __builtin_amdgcn_sched_barrier(0)

// ---------------------------------------------------------------------------
// R12: B operand DIRECT-TO-REGISTER.  R11 post-mortem: LDS pipe was the long
// pole (128 KiB/step = reads 96 + gload_lds writes 32 ~ 1540 cyc vs MFMA
// 1242; measured 2240).  B frags are only 2-wave-shared, so each wave loads
// its own B straight from global (4x global_load_dwordx4, 16 rows x 64 B
// contiguous per instr, byte-identical fragment) -> LDS drops to 80 KiB/step
// (~940 cyc) and MFMA becomes the critical pipe.
//   - A: unchanged 4-slot global_load_lds protocol (2 loads/step, 64 KiB LDS)
//   - B: single reg bank; B(t+1) issued AFTER step t's MFMAs (regs just
//     freed), gated next step by counted vmcnt (per-wave private -> no
//     barrier needed for B visibility)
//   - per-step vm order: [A-stage(t+3) x2][gate vmcnt][MFMA][B(t+1) x4]
//     [boundary vmcnt(6) = keep B(t+1)4 + Astage2][ONE barrier]
//
// M padded to 6400: no tail blocks; conv1 blocks exactly 9 taps (288 steps).
// LDS k-swizzle unchanged: conflict-free ds_read_b128.
// A: P [t=0..8][6][16][16][1024] bf16; B: Wt [27][COUT][1024].
// sched entry: x2:5 | n:2 | z:3 | tap0:5 | tap1:5
// ---------------------------------------------------------------------------
template <int COUT, bool TCOND>
__global__ __launch_bounds__(512, 2) void conv_gemm(
    const unsigned short* __restrict__ P,
    const unsigned short* __restrict__ Wt,
    const unsigned int* __restrict__ sched,
    unsigned short* __restrict__ part)
{
  constexpr int CIN = 1024;
  __shared__ short lA[4][8192];   // 4 slots x 16 KiB (A only; B bypasses LDS)
  const int tid  = threadIdx.x;
  const int wave = tid >> 6;
  const int lane = tid & 63;

  const unsigned int e = sched[blockIdx.x];
  const int x2   = e & 31;
  const int nidx = (e >> 5) & 3;
  const int zs   = (e >> 7) & 7;
  const int tap0 = (e >> 10) & 31;
  const int tap1 = (e >> 15) & 31;
  const int m0 = x2 * 256;
  const int n0 = nidx * 256;
  unsigned short* partOut = part + (size_t)zs * M_PAD * COUT;

  // Tile-level depth-tap validity over spanned REAL (t,d) cells (pad excluded).
  bool kdv[3] = {false, false, false};
  {
    const int cA = m0 / 196;
    int cB = (m0 + 255) / 196; if (cB > 31) cB = 31;
    for (int c = cA; c <= cB; ++c) {
      int t = c >> 2, d = c & 3;
      #pragma unroll
      for (int kd = 0; kd < 3; ++kd) {
        int s = d + kd;
        bool ok = (s >= 1) && (s <= 4);
        if (TCOND) ok = ok && (s >= 5 - t);
        kdv[kd] = kdv[kd] || ok;
      }
    }
  }

  // A staging geometry (row = tid>>2 within 128-row half, seg = tid&3);
  // global source pre-swizzled: chunk (tid&3) ^ ((row>>1)&3).
  const int arow = tid >> 2;
  const int aswz = (((tid & 3) ^ ((arow >> 1) & 3)) << 4);
  int aG[2];
  #pragma unroll
  for (int q = 0; q < 2; ++q) {
    int m = m0 + q * 128 + arow;
    int t = m / 784;  int r2 = m - t * 784;
    int d = r2 / 196; int r3 = r2 - d * 196;
    int h = r3 / 14;  int w = r3 - h * 14;
    aG[q] = ((((t * 6 + d) * 16 + h) * 16 + w) * CIN) * 2 + aswz;
  }

  // Step stream: 32 K-steps per valid tap.  Two iterators:
  //   itA (A staging, 3 steps ahead) and itB (B reg loads, 1 step ahead).
  int nvt = 0;
  for (int tp = tap0; tp < tap1; ++tp) if (kdv[tp / 9]) ++nvt;
  const int steps = nvt * 32;                 // >= 32 for all scheduled blocks
  int tapA = tap0;
  while (tapA < tap1 && !kdv[tapA / 9]) ++tapA;
  int cA2 = 0;
  int tapB = tapA, cB2 = 0;
  auto stepA = [&]() -> int {
    const int kd = tapA / 9, rm = tapA - kd * 9;
    const int kh = rm / 3, kw = rm - kh * 3;
    const int st = ((((kd * 16) + kh) * 16 + kw) * CIN) * 2 + cA2 * 2;
    cA2 += 32;
    if (cA2 == CIN) { cA2 = 0; do { ++tapA; } while (tapA < tap1 && !kdv[tapA / 9]); }
    return st;
  };
  auto stepB = [&]() -> int {
    const int st = tapB * (COUT * CIN * 2) + cB2 * 2;
    cB2 += 32;
    if (cB2 == CIN) { cB2 = 0; do { ++tapB; } while (tapB < tap1 && !kdv[tapB / 9]); }
    return st;
  };

  const char* Pb = (const char*)P;
  const char* Wb = (const char*)Wt;
  char* lAc = (char*)&lA[0][0];
  const unsigned ldsA0 =
      (unsigned)(size_t)(__attribute__((address_space(3))) char*)lAc;

  const int wm   = (wave >> 2) * 128;
  const int wn   = (wave & 3) * 64;
  const int quad = lane >> 4;
  const int l15  = lane & 15;
  const int segc = ((quad ^ ((l15 >> 1) & 3)) << 4);
  const unsigned rowA = ((unsigned)(wm + l15) << 6) + segc;   // + i*1024 imm
  // B per-lane global row offset: row (n0+wn+j*16+l15), k-chunk quad*8 elems.
  const size_t bRowOff = ((size_t)(n0 + wn + l15) * CIN + (size_t)quad * 8) * 2;

  int4v b0, b1, b2, b3;

  // Prologue: stage A slots 0..2 (6 vm loads), load B(0) (4 vm loads),
  // retire slot 0's A (vmcnt(8) keeps A1,A2,B0 in flight), barrier.
  #pragma unroll 1
  for (int s = 0; s < 3; ++s) {
    const int st = stepA();
    char* dA = lAc + s * 16384;
    async_ld16(Pb + aG[0] + st, dA + tid * 16);
    async_ld16(Pb + aG[1] + st, dA + 8192 + tid * 16);
  }
  SB0;
  {
    const char* bp = Wb + (size_t)stepB() + bRowOff;
    GLB(b0, bp);
    GLB(b1, bp + 32768);
    GLB(b2, bp + 65536);
    GLB(b3, bp + 98304);
  }
  SB0;
  asm volatile("s_waitcnt vmcnt(8)" ::: "memory");
  __builtin_amdgcn_s_barrier();
  SB0;

  floatx4 acc[8][4];
  const floatx4 zero4 = {0.f, 0.f, 0.f, 0.f};
  #pragma unroll
  for (int i = 0; i < 8; ++i)
    #pragma unroll
    for (int j = 0; j < 4; ++j) acc[i][j] = zero4;

  #pragma unroll 1
  for (int t = 0; t < steps; ++t) {
    const unsigned aBase = ldsA0 + (unsigned)(t & 3) * 16384u + rowA;
    const bool h3s = (t + 3 < steps);
    const bool hB  = (t + 1 < steps);

    // A ds_reads, pinned order a0..a7 (lgkm).
    int4v av[8];
    DSR(av[0], aBase, 0);
    DSR(av[1], aBase, 1024);
    DSR(av[2], aBase, 2048);
    DSR(av[3], aBase, 3072);
    DSR(av[4], aBase, 4096);
    DSR(av[5], aBase, 5120);
    DSR(av[6], aBase, 6144);
    DSR(av[7], aBase, 7168);
    SB0;

    // A staging for step t+3 into dead slot (t-1)&3 (2 vm loads).
    if (h3s) {
      const int st = stepA();
      char* dA = lAc + ((t + 3) & 3) * 16384;
      async_ld16(Pb + aG[0] + st, dA + tid * 16);
      async_ld16(Pb + aG[1] + st, dA + 8192 + tid * 16);
    }
    SB0;

    // Gate: retire B(t) (issued end of step t-1).  Newer vm = A-stage (2) if
    // issued this step, else 0.
    if (h3s) { asm volatile("s_waitcnt vmcnt(2)" ::: "memory"); }
    else     { asm volatile("s_waitcnt vmcnt(0)" ::: "memory"); }
    SB0;

    short8 bs[4];
    bs[0] = __builtin_bit_cast(short8, b0);
    bs[1] = __builtin_bit_cast(short8, b1);
    bs[2] = __builtin_bit_cast(short8, b2);
    bs[3] = __builtin_bit_cast(short8, b3);

    // Counted-lgkm ladder: group i ready when (7-i) A reads outstanding.
    __builtin_amdgcn_s_setprio(1);
    WAITL(7);
    {
      short8 a = __builtin_bit_cast(short8, av[0]);
      #pragma unroll
      for (int j = 0; j < 4; ++j)
        acc[0][j] = __builtin_amdgcn_mfma_f32_16x16x32_bf16(a, bs[j], acc[0][j], 0, 0, 0);
    }
    WAITL(6);
    {
      short8 a = __builtin_bit_cast(short8, av[1]);
      #pragma unroll
      for (int j = 0; j < 4; ++j)
        acc[1][j] = __builtin_amdgcn_mfma_f32_16x16x32_bf16(a, bs[j], acc[1][j], 0, 0, 0);
    }
    WAITL(5);
    {
      short8 a = __builtin_bit_cast(short8, av[2]);
      #pragma unroll
      for (int j = 0; j < 4; ++j)
        acc[2][j] = __builtin_amdgcn_mfma_f32_16x16x32_bf16(a, bs[j], acc[2][j], 0, 0, 0);
    }
    WAITL(4);
    {
      short8 a = __builtin_bit_cast(short8, av[3]);
      #pragma unroll
      for (int j = 0; j < 4; ++j)
        acc[3][j] = __builtin_amdgcn_mfma_f32_16x16x32_bf16(a, bs[j], acc[3][j], 0, 0, 0);
    }
    WAITL(3);
    {
      short8 a = __builtin_bit_cast(short8, av[4]);
      #pragma unroll
      for (int j = 0; j < 4; ++j)
        acc[4][j] = __builtin_amdgcn_mfma_f32_16x16x32_bf16(a, bs[j], acc[4][j], 0, 0, 0);
    }
    WAITL(2);
    {
      short8 a = __builtin_bit_cast(short8, av[5]);
      #pragma unroll
      for (int j = 0; j < 4; ++j)
        acc[5][j] = __builtin_amdgcn_mfma_f32_16x16x32_bf16(a, bs[j], acc[5][j], 0, 0, 0);
    }
    WAITL(1);
    {
      short8 a = __builtin_bit_cast(short8, av[6]);
      #pragma unroll
      for (int j = 0; j < 4; ++j)
        acc[6][j] = __builtin_amdgcn_mfma_f32_16x16x32_bf16(a, bs[j], acc[6][j], 0, 0, 0);
    }
    WAITL(0);
    {
      short8 a = __builtin_bit_cast(short8, av[7]);
      #pragma unroll
      for (int j = 0; j < 4; ++j)
        acc[7][j] = __builtin_amdgcn_mfma_f32_16x16x32_bf16(a, bs[j], acc[7][j], 0, 0, 0);
    }
    __builtin_amdgcn_s_setprio(0);
    SB0;

    // Issue B(t+1) into the just-freed reg bank (4 vm loads, per-wave).
    if (hB) {
      const char* bp = Wb + (size_t)stepB() + bRowOff;
      GLB(b0, bp);
      GLB(b1, bp + 32768);
      GLB(b2, bp + 65536);
      GLB(b3, bp + 98304);
    }
    SB0;

    // Boundary: retire A slot t+1's staging (issued step t-2); keep
    // B(t+1) (4) + A-stage(t+3) (2) in flight.  ONE barrier per step.
    if (h3s)      { asm volatile("s_waitcnt vmcnt(6)" ::: "memory"); }
    else if (hB)  { asm volatile("s_waitcnt vmcnt(4)" ::: "memory"); }
    else          { asm volatile("s_waitcnt vmcnt(0)" ::: "memory"); }
    SB0;
    __builtin_amdgcn_s_barrier();
    SB0;
  }

  // Full drain before epilogue (nothing may leak past kernel end).
  asm volatile("s_waitcnt vmcnt(0) lgkmcnt(0)" ::: "memory");
  __builtin_amdgcn_s_barrier();

  // Epilogue: C/D layout col=lane&15, row=quad*4+reg. Raw bf16 partials.
  #pragma unroll
  for (int j = 0; j < 4; ++j) {
    const int o = n0 + wn + j * 16 + l15;
    #pragma unroll
    for (int i = 0; i < 8; ++i) {
      #pragma unroll
      for (int r = 0; r < 4; ++r) {
        int m = m0 + wm + i * 16 + quad * 4 + r;
        partOut[(size_t)m * COUT + o] = f2bf(acc[i][j][r]);
      }
    }
  }
}

// ---------------------------------------------------------------------------
// reduce1: sum 3 bf16 partial slices + bias, relu, cast bf16, scatter into
// padded P2 layout [t][6][16][16][1024] (interior only; halo pre-zeroed).
// ---------------------------------------------------------------------------
__global__ void reduce_conv1(const unsigned short* __restrict__ part,
                             const float* __restrict__ bias,
                             unsigned short* __restrict__ P2) {
  const int idx = blockIdx.x * 256 + threadIdx.x;
  const int m  = idx >> 8;
  const int o4 = (idx & 255) * 4;
  const size_t ss = (size_t)M_PAD * 1024;
  const size_t base = (size_t)m * 1024 + o4;
  ushort4v p0 = *(const ushort4v*)(part + base);
  ushort4v p1 = *(const ushort4v*)(part + ss + base);
  ushort4v p2 = *(const ushort4v*)(part + 2 * ss + base);
  ushort4v out;
  #pragma unroll
  for (int k = 0; k < 4; ++k) {
    float v = bf2f(p0[k]) + bf2f(p1[k]) + bf2f(p2[k]) + bias[o4 + k];
    out[k] = f2bf(v > 0.f ? v : 0.f);
  }
  int t = m / 784;  int r2 = m - t * 784;
  int d = r2 / 196; int r3 = r2 - d * 196;
  int h = r3 / 14;  int w = r3 - h * 14;
  size_t didx = (size_t)(((t * 6 + d + 1) * 16 + (h + 1)) * 16 + (w + 1)) * 1024 + o4;
  *(ushort4v*)(P2 + didx) = out;
}

// ---------------------------------------------------------------------------
// reduce2: sum 5 bf16 partial slices + bias, relu, cast bf16 -> h2 [6272][512].
// ---------------------------------------------------------------------------
__global__ void reduce_conv2(const unsigned short* __restrict__ part,
                             const float* __restrict__ bias,
                             unsigned short* __restrict__ h2) {
  const int idx = blockIdx.x * 256 + threadIdx.x;
  const int m  = idx >> 7;
  const int o4 = (idx & 127) * 4;
  const size_t base = (size_t)m * 512 + o4;
  const size_t ss = (size_t)M_PAD * 512;
  float acc[4];
  #pragma unroll
  for (int k = 0; k < 4; ++k) acc[k] = bias[o4 + k];
  #pragma unroll
  for (int s = 0; s < 5; ++s) {
    ushort4v p = *(const ushort4v*)(part + (size_t)s * ss + base);
    #pragma unroll
    for (int k = 0; k < 4; ++k) acc[k] += bf2f(p[k]);
  }
  ushort4v out;
  #pragma unroll
  for (int k = 0; k < 4; ++k) out[k] = f2bf(acc[k] > 0.f ? acc[k] : 0.f);
  *(ushort4v*)(h2 + base) = out;
}

// ---------------------------------------------------------------------------
// Max-pool, two-stage. h2 bf16 >= 0 -> bit pattern monotone -> max raw ushorts.
// ---------------------------------------------------------------------------
__global__ void pool1(const unsigned short* __restrict__ h2,
                      unsigned short* __restrict__ partial) {
  const int t = blockIdx.x / 28, ch = blockIdx.x % 28, o = threadIdx.x;
  const unsigned short* src = h2 + ((size_t)t * 784 + ch * 28) * 512 + o;
  unsigned short m = 0;
  #pragma unroll 4
  for (int i = 0; i < 28; ++i) { unsigned short v = src[(size_t)i * 512]; m = v > m ? v : m; }
  partial[((size_t)t * 28 + ch) * 512 + o] = m;
}

__global__ void pool2(const unsigned short* __restrict__ partial, float* __restrict__ pooled) {
  const int t = blockIdx.x, o = threadIdx.x;
  const unsigned short* src = partial + (size_t)t * 28 * 512 + o;
  unsigned short m = 0;
  #pragma unroll 4
  for (int i = 0; i < 28; ++i) { unsigned short v = src[(size_t)i * 512]; m = v > m ? v : m; }
  pooled[t * 512 + o] = bf2f(m);
}

// ---------------------------------------------------------------------------
// Tiny MLP, fp32. Block per t, 512 threads.
// ---------------------------------------------------------------------------
__global__ void mlp_kernel(const float* __restrict__ pooled,
                           const float* __restrict__ w1, const float* __restrict__ b1,
                           const float* __restrict__ w2, const float* __restrict__ b2,
                           const float* __restrict__ w3, const float* __restrict__ b3,
                           float* __restrict__ out) {
  const int t = blockIdx.x, j = threadIdx.x;
  __shared__ float xa[512], xb[512];
  xa[j] = pooled[t * 512 + j];
  __syncthreads();
  {
    const float4* wr = (const float4*)(w1 + (size_t)j * 512);
    float s = b1[j];
    #pragma unroll 4
    for (int k = 0; k < 128; ++k) {
      float4 wv = wr[k];
      s += wv.x * xa[4*k] + wv.y * xa[4*k+1] + wv.z * xa[4*k+2] + wv.w * xa[4*k+3];
    }
    xb[j] = fmaxf(s, 0.f);
  }
  __syncthreads();
  {
    const float4* wr = (const float4*)(w2 + (size_t)j * 512);
    float s = b2[j];
    #pragma unroll 4
    for (int k = 0; k < 128; ++k) {
      float4 wv = wr[k];
      s += wv.x * xb[4*k] + wv.y * xb[4*k+1] + wv.z * xb[4*k+2] + wv.w * xb[4*k+3];
    }
    xa[j] = fmaxf(s, 0.f);
  }
  __syncthreads();
  if (j < 128) {
    const float4* wr = (const float4*)(w3 + (size_t)j * 512);
    float s = b3[j];
    #pragma unroll 4
    for (int k = 0; k < 128; ++k) {
      float4 wv = wr[k];
      s += wv.x * xa[4*k] + wv.y * xa[4*k+1] + wv.z * xa[4*k+2] + wv.w * xa[4*k+3];
    }
    out[t * 128 + j] = fmaxf(s, 0.f);
  }
}

// ---------------------------------------------------------------------------
// Host schedule: per block (m-tile x2, n-tile, K-slice z, tap range).
// conv1: ns = nv/9 -> every block exactly 9 valid taps (uniform, 288 steps).
// conv2: ns = 5 (27 taps) or 4 (18 taps).  Grid <= 256 at 1 block/CU;
// XCD-grouped interleave (block g -> XCD g%8 contiguous chunk).
// ---------------------------------------------------------------------------
static int build_sched(bool conv1, unsigned int* out) {
  const int nt = conv1 ? 4 : 2;
  unsigned int L[256];
  int cnt = 0;
  for (int n = 0; n < nt; ++n) {
    for (int x2 = 0; x2 < 25; ++x2) {
      const int m0 = x2 * 256;
      bool kdv[3] = {false, false, false};
      const int cA = m0 / 196;
      int cB = (m0 + 255) / 196; if (cB > 31) cB = 31;
      for (int c = cA; c <= cB; ++c) {
        int t = c >> 2, d = c & 3;
        for (int kd = 0; kd < 3; ++kd) {
          int s = d + kd;
          bool ok = (s >= 1 && s <= 4);
          if (conv1) ok = ok && (s >= 5 - t);
          kdv[kd] = kdv[kd] || ok;
        }
      }
      int vt[27], nv = 0;
      for (int tp = 0; tp < 27; ++tp) if (kdv[tp / 9]) vt[nv++] = tp;
      if (!nv) continue;
      const int ns = conv1 ? (nv / 9) : ((nv == 27) ? 5 : 4);
      for (int s = 0; s < ns; ++s) {
        int b0 = nv * s / ns, b1 = nv * (s + 1) / ns;
        int tp0 = vt[b0], tp1 = vt[b1 - 1] + 1;
        L[cnt++] = (unsigned int)(x2 | (n << 5) | (s << 7) | (tp0 << 10) | (tp1 << 15));
      }
    }
  }
  const int q = cnt / 8, r = cnt % 8;
  int pos = 0;
  for (int b = 0; b < 8; ++b) {
    const int nb = q + (b < r ? 1 : 0);
    for (int j = 0; j < nb; ++j) out[j * 8 + b] = L[pos++];
  }
  return cnt;
}

// ---------------------------------------------------------------------------
// Workspace layout (bytes) — total 122,685,440:
//   P12 (P1/P2, 51 slots incl t=8 pad) @ 0         : 26,738,688
//   W1t                       @ 26,738,688         : 56,623,104  (dead after gemm1)
//     W2t  (aliases W1t)      @ 26,738,688         : 28,311,552  (built after gemm1)
//     h2                      @ 55,050,240         :  6,422,528
//     pooled                  @ 61,472,768         :     16,384
//     ppart                   @ 61,489,152         :    229,376
//   part                      @ 83,361,792         : 39,321,600  (conv1 3x6400x1024,
//                                                    conv2 5x6400x512 = 32,768,000)
//   sched1 / sched2           @ 122,683,392 / 122,684,416 : 1,024 each
// ---------------------------------------------------------------------------
extern "C" void kernel_launch(void* const* d_in, const int* in_sizes, int n_in,
                              void* d_out, int out_size, void* d_ws, size_t ws_size,
                              hipStream_t stream) {
  const float* videos = (const float*)d_in[0];
  const float* c1w = (const float*)d_in[1];
  const float* c1b = (const float*)d_in[2];
  const float* c2w = (const float*)d_in[3];
  const float* c2b = (const float*)d_in[4];
  const float* l1w = (const float*)d_in[5];
  const float* l1b = (const float*)d_in[6];
  const float* l2w = (const float*)d_in[7];
  const float* l2b = (const float*)d_in[8];
  const float* l3w = (const float*)d_in[9];
  const float* l3b = (const float*)d_in[10];

  char* ws = (char*)d_ws;
  unsigned short* P12   = (unsigned short*)(ws);
  unsigned short* W1t   = (unsigned short*)(ws + 26738688);
  unsigned short* W2t   = (unsigned short*)(ws + 26738688);   // aliases W1t
  unsigned short* h2    = (unsigned short*)(ws + 55050240);
  float*          pooled= (float*)(ws + 61472768);
  unsigned short* ppart = (unsigned short*)(ws + 61489152);
  unsigned short* part  = (unsigned short*)(ws + 83361792);
  unsigned int* dsched1 = (unsigned int*)(ws + 122683392);
  unsigned int* dsched2 = (unsigned int*)(ws + 122684416);
  float* out = (float*)d_out;

  // Host scheds: static so captured memcpy sources persist across graph replays.
  static unsigned int s1h[256], s2h[256];
  const int n1 = build_sched(true,  s1h);   // 228 blocks, all 9-tap uniform
  const int n2 = build_sched(false, s2h);   // 248 blocks
  hipMemcpyAsync(dsched1, s1h, sizeof(s1h), hipMemcpyHostToDevice, stream);
  hipMemcpyAsync(dsched2, s2h, sizeof(s2h), hipMemcpyHostToDevice, stream);

  // Zero padded activation buffer (halo + unused windows + t=8 pad slots).
  hipMemsetAsync(ws, 0, 26738688, stream);
  // Zero conv1 partials (empty m-tiles + unused slices).
  hipMemsetAsync(part, 0, 39321600, stream);

  wtrans<<<4096, 256, 0, stream>>>(c1w, W1t, 1024 * 1024);
  build_P1<<<dim3(8, 16), 256, 0, stream>>>(videos, P12);

  conv_gemm<1024, true ><<<n1, 512, 0, stream>>>(P12, W1t, dsched1, part);

  // W2t overwrites W1t — only after conv_gemm1 is done (stream order).
  wtrans<<<2048, 256, 0, stream>>>(c2w, W2t, 512 * 1024);
  reduce_conv1<<<6272, 256, 0, stream>>>(part, c1b, P12);
  // conv2: x2=24 blocks have 4 slices; zero z=4 rows 6144.. (after reduce1!).
  hipMemsetAsync((char*)part + 32505856, 0, 262144, stream);

  conv_gemm<512, false><<<n2, 512, 0, stream>>>(P12, W2t, dsched2, part);
  reduce_conv2<<<3136, 256, 0, stream>>>(part, c2b, h2);

  pool1<<<224, 512, 0, stream>>>(h2, ppart);
  pool2<<<8, 512, 0, stream>>>(ppart, pooled);
  mlp_kernel<<<8, 512, 0, stream>>>(pooled, l1w, l1b, l2w, l2b, l3w, l3b, out);
}

// Round 9
// 748.047 us; speedup vs baseline: 1.2330x; 1.2330x over previous
//
#include <hip/hip_runtime.h>

typedef __attribute__((ext_vector_type(8))) short short8;
typedef __attribute__((ext_vector_type(4))) int int4v;
typedef __attribute__((ext_vector_type(4))) float floatx4;
typedef __attribute__((ext_vector_type(4))) unsigned short ushort4v;

#define DEV __device__ __forceinline__

constexpr int M_TOT = 6272;   // 8 * 784 real output positions
constexpr int M_PAD = 6400;   // padded to 25*256 (pad rows read zeroed P slots)

DEV void async_ld16(const void* g, void* l) {
  __builtin_amdgcn_global_load_lds(
      (const __attribute__((address_space(1))) unsigned int*)g,
      (__attribute__((address_space(3))) unsigned int*)l,
      16, 0, 0);
}

DEV unsigned short f2bf(float x) {
  union { float f; unsigned int u; } v; v.f = x;
  unsigned int u = v.u;
  u += 0x7FFFu + ((u >> 16) & 1u);   // round-to-nearest-even
  return (unsigned short)(u >> 16);
}

DEV float bf2f(unsigned short s) {
  union { unsigned int u; float f; } v; v.u = ((unsigned int)s) << 16;
  return v.f;
}

// ---------------------------------------------------------------------------
// Weight transform: conv_w fp32 [O][C][3][3][3] -> bf16 [tap][o][c]  (B^T).
// ---------------------------------------------------------------------------
__global__ void wtrans(const float* __restrict__ w, unsigned short* __restrict__ wt,
                       int total /* = O*C, multiple of 256 */) {
  __shared__ unsigned short l[256 * 27];
  const int tid  = threadIdx.x;
  const int base = blockIdx.x * 256;
  #pragma unroll 1
  for (int j = tid; j < 256 * 27; j += 256)
    l[j] = f2bf(w[(size_t)base * 27 + j]);
  __syncthreads();
  #pragma unroll 1
  for (int tap = 0; tap < 27; ++tap)
    wt[(size_t)tap * total + base + tid] = l[tid * 27 + tap];
}

// ---------------------------------------------------------------------------
// Build P1: videos fp32 [8][1024][14][14] -> P1 bf16 [t=8][s=6][16][16][1024]
// P1[t][s][h+1][w+1][c] = videos[t-5+s][c][h][w] for s in 1..4 (else zero).
// ---------------------------------------------------------------------------
__global__ void build_P1(const float* __restrict__ videos, unsigned short* __restrict__ P1) {
  const int f  = blockIdx.x;
  const int c0 = blockIdx.y * 64;
  const int tid = threadIdx.x;
  __shared__ unsigned short tile[64][196];

  #pragma unroll 1
  for (int it = 0; it < 49; ++it) {       // 49*256 = 64*196 exactly
    int idx = it * 256 + tid;
    int c = idx / 196, r = idx - c * 196;
    tile[c][r] = f2bf(videos[(size_t)(f * 1024 + c0 + c) * 196 + r]);
  }
  __syncthreads();

  const int c   = tid & 63;
  const int hwq = tid >> 6;
  #pragma unroll 1
  for (int s = 1; s <= 4; ++s) {
    int t = f + 5 - s;
    if (t > 7) continue;
    unsigned short* dst = P1 + (size_t)(t * 6 + s) * 256 * 1024 + (size_t)c0;
    #pragma unroll 1
    for (int it = 0; it < 49; ++it) {
      int hw = it * 4 + hwq;
      int h = hw / 14, w = hw - h * 14;
      dst[(size_t)((h + 1) * 16 + (w + 1)) * 1024 + c] = tile[c][hw];
    }
  }
}

// Pinned-order LDS read (issue order = program order among volatile asm).
#define DSR(dst, addr, off) \
  asm volatile("ds_read_b128 %0, %1 offset:" #off : "=&v"(dst) : "v"(addr))
#define WAITL(n) \
  asm volatile("s_waitcnt lgkmcnt(" #n ")" ::: "memory"); \
  __builtin_amdgcn_sched_barrier(0)
#define SB0 __builtin_amdgcn_sched_barrier(0)

// ---------------------------------------------------------------------------
// R13: cross-step PRE-READ on the R10 quad-buffer pipeline (B back in LDS —
// R12's global-B scatter regressed).  R10/R11 step = 2240 cyc vs floors
// (MFMA 1242, LDS ~1400): the 96-read burst after each barrier gated MFMA
// start.  Fix: retire staging one step earlier (boundary vmcnt(4), strictly
// more conservative than R10's vmcnt(8); ~1.5-step latency cover), so slot
// u+1 is resident DURING step u; after step u's MFMAs, pre-read step u+1's
// first 6 frags (b0..b3,a0,a1) into the alternate bank — they drain across
// the barrier.  Step top issues only a2..a7 fresh; ladder counts unchanged
// (retire order b0..3,a0..a7; group i waits lgkmcnt(7-i)).  Banks are
// double-buffered via 2-step unroll with named registers (steps = nvt*32,
// always even).  ONE barrier per step; slot protocol:
//  - stage slot s issued step s-3; boundary u vmcnt(4) retires stages <= u+2
//    -> after boundary u-1, slots <= u+1 resident (fresh+pre reads valid)
//  - staging target (u+3)&3 == (u-1)&3: its last reads were the pre-reads
//    during step u-2, retired by that step's ladder, sealed by barrier u-1.
//
// M padded to 6400: no tail blocks; conv1 blocks exactly 9 taps (288 steps).
// LDS k-swizzle: LDS(row,seg) holds chunk seg ^ ((row>>1)&3); read seg =
// quad ^ ((l15>>1)&3) -> conflict-free b128 (SQ_LDS_BANK_CONFLICT == 0).
// A: P [t=0..8][6][16][16][1024] bf16; B: Wt [27][COUT][1024].
// sched entry: x2:5 | n:2 | z:3 | tap0:5 | tap1:5
// ---------------------------------------------------------------------------
template <int COUT, bool TCOND>
__global__ __launch_bounds__(512, 2) void conv_gemm(
    const unsigned short* __restrict__ P,
    const unsigned short* __restrict__ Wt,
    const unsigned int* __restrict__ sched,
    unsigned short* __restrict__ part)
{
  constexpr int CIN = 1024;
  __shared__ short lA[4][8192];   // 4 slots x 16 KiB  (256 rows x 32 k)
  __shared__ short lB[4][8192];
  const int tid  = threadIdx.x;
  const int wave = tid >> 6;
  const int lane = tid & 63;

  const unsigned int e = sched[blockIdx.x];
  const int x2   = e & 31;
  const int nidx = (e >> 5) & 3;
  const int zs   = (e >> 7) & 7;
  const int tap0 = (e >> 10) & 31;
  const int tap1 = (e >> 15) & 31;
  const int m0 = x2 * 256;
  const int n0 = nidx * 256;
  unsigned short* partOut = part + (size_t)zs * M_PAD * COUT;

  // Tile-level depth-tap validity over spanned REAL (t,d) cells (pad excluded).
  bool kdv[3] = {false, false, false};
  {
    const int cA = m0 / 196;
    int cB = (m0 + 255) / 196; if (cB > 31) cB = 31;
    for (int c = cA; c <= cB; ++c) {
      int t = c >> 2, d = c & 3;
      #pragma unroll
      for (int kd = 0; kd < 3; ++kd) {
        int s = d + kd;
        bool ok = (s >= 1) && (s <= 4);
        if (TCOND) ok = ok && (s >= 5 - t);
        kdv[kd] = kdv[kd] || ok;
      }
    }
  }

  // Staging geometry: thread covers (row = tid>>2 within 128-row half,
  // seg = tid&3); global source pre-swizzled: chunk (tid&3) ^ ((row>>1)&3).
  const int arow = tid >> 2;
  const int aswz = (((tid & 3) ^ ((arow >> 1) & 3)) << 4);
  int aG[2], bG[2];
  #pragma unroll
  for (int q = 0; q < 2; ++q) {
    int m = m0 + q * 128 + arow;
    int t = m / 784;  int r2 = m - t * 784;
    int d = r2 / 196; int r3 = r2 - d * 196;
    int h = r3 / 14;  int w = r3 - h * 14;
    aG[q] = ((((t * 6 + d) * 16 + h) * 16 + w) * CIN) * 2 + aswz;
    bG[q] = (n0 + q * 128 + arow) * (CIN * 2) + aswz;
  }

  // Step stream: 32 K-steps per valid tap (steps = nvt*32, even, >= 32).
  int nvt = 0;
  for (int tp = tap0; tp < tap1; ++tp) if (kdv[tp / 9]) ++nvt;
  const int steps = nvt * 32;
  int tap_s = tap0;
  while (tap_s < tap1 && !kdv[tap_s / 9]) ++tap_s;
  int c_s = 0;
  int stA = 0, stB = 0;
  auto setBases = [&]() {
    const int kd = tap_s / 9, rm = tap_s - kd * 9;
    const int kh = rm / 3, kw = rm - kh * 3;
    stA = ((((kd * 16) + kh) * 16 + kw) * CIN) * 2 + c_s * 2;
    stB = tap_s * (COUT * CIN * 2) + c_s * 2;
  };
  auto adv = [&]() {
    c_s += 32;
    if (c_s == CIN) { c_s = 0; do { ++tap_s; } while (tap_s < tap1 && !kdv[tap_s / 9]); }
  };

  const char* Pb = (const char*)P;
  const char* Wb = (const char*)Wt;
  char* lAc = (char*)&lA[0][0];
  char* lBc = (char*)&lB[0][0];
  const unsigned ldsA0 =
      (unsigned)(size_t)(__attribute__((address_space(3))) char*)lAc;
  const unsigned ldsB0 =
      (unsigned)(size_t)(__attribute__((address_space(3))) char*)lBc;

  // Prologue: stage slots 0,1,2 (12 vm loads); vmcnt(4) retires slots 0,1
  // (keeps stage-2 in flight); barrier.
  #pragma unroll 1
  for (int s = 0; s < 3; ++s) {
    setBases();
    char* dA = lAc + s * 16384;
    char* dB = lBc + s * 16384;
    async_ld16(Pb + aG[0] + stA, dA + tid * 16);
    async_ld16(Wb + bG[0] + stB, dB + tid * 16);
    async_ld16(Pb + aG[1] + stA, dA + 8192 + tid * 16);
    async_ld16(Wb + bG[1] + stB, dB + 8192 + tid * 16);
    adv();
  }
  asm volatile("s_waitcnt vmcnt(4)" ::: "memory");
  __builtin_amdgcn_s_barrier();
  SB0;

  const int wm   = (wave >> 2) * 128;
  const int wn   = (wave & 3) * 64;
  const int quad = lane >> 4;
  const int l15  = lane & 15;
  const int segc = ((quad ^ ((l15 >> 1) & 3)) << 4);
  const unsigned rowA = ((unsigned)(wm + l15) << 6) + segc;   // + i*1024 imm
  const unsigned rowB = ((unsigned)(wn + l15) << 6) + segc;   // + j*1024 imm

  floatx4 acc[8][4];
  const floatx4 zero4 = {0.f, 0.f, 0.f, 0.f};
  #pragma unroll
  for (int i = 0; i < 8; ++i)
    #pragma unroll
    for (int j = 0; j < 4; ++j) acc[i][j] = zero4;

  // Pre-read banks (E: even steps, O: odd steps).  Constant indices only.
  int4v pbE0, pbE1, pbE2, pbE3, paE0, paE1;
  int4v pbO0, pbO1, pbO2, pbO3, paO0, paO1;

  // Prologue pre-read for step 0 (slot 0 resident after vmcnt(4)+barrier).
  {
    const unsigned aB = ldsA0 + rowA;
    const unsigned bB = ldsB0 + rowB;
    DSR(pbE0, bB, 0);
    DSR(pbE1, bB, 1024);
    DSR(pbE2, bB, 2048);
    DSR(pbE3, bB, 3072);
    DSR(paE0, aB, 0);
    DSR(paE1, aB, 1024);
  }
  SB0;

#define MFMA_GRP(ACCI, AV)                                                  \
  {                                                                         \
    short8 a_ = __builtin_bit_cast(short8, AV);                             \
    acc[ACCI][0] = __builtin_amdgcn_mfma_f32_16x16x32_bf16(a_, bs0, acc[ACCI][0], 0, 0, 0); \
    acc[ACCI][1] = __builtin_amdgcn_mfma_f32_16x16x32_bf16(a_, bs1, acc[ACCI][1], 0, 0, 0); \
    acc[ACCI][2] = __builtin_amdgcn_mfma_f32_16x16x32_bf16(a_, bs2, acc[ACCI][2], 0, 0, 0); \
    acc[ACCI][3] = __builtin_amdgcn_mfma_f32_16x16x32_bf16(a_, bs3, acc[ACCI][3], 0, 0, 0); \
  }

#define STEP_BODY(U, PB0, PB1, PB2, PB3, PA0, PA1, NB0, NB1, NB2, NB3, NA0, NA1) \
  {                                                                         \
    const int u_ = (U);                                                     \
    const bool h3s = (u_ + 3 < steps);                                      \
    const unsigned aB = ldsA0 + (unsigned)(u_ & 3) * 16384u + rowA;         \
    int4v f2, f3, f4, f5, f6, f7;                                           \
    DSR(f2, aB, 2048);                                                      \
    DSR(f3, aB, 3072);                                                      \
    DSR(f4, aB, 4096);                                                      \
    DSR(f5, aB, 5120);                                                      \
    DSR(f6, aB, 6144);                                                      \
    DSR(f7, aB, 7168);                                                      \
    SB0;                                                                    \
    if (h3s) {                                                              \
      setBases();                                                           \
      char* dA = lAc + ((u_ + 3) & 3) * 16384;                              \
      char* dB = lBc + ((u_ + 3) & 3) * 16384;                              \
      async_ld16(Pb + aG[0] + stA, dA + tid * 16);                          \
      async_ld16(Wb + bG[0] + stB, dB + tid * 16);                          \
      async_ld16(Pb + aG[1] + stA, dA + 8192 + tid * 16);                   \
      async_ld16(Wb + bG[1] + stB, dB + 8192 + tid * 16);                   \
      adv();                                                                \
    }                                                                       \
    SB0;                                                                    \
    __builtin_amdgcn_s_setprio(1);                                          \
    short8 bs0, bs1, bs2, bs3;                                              \
    WAITL(7);                                                               \
    bs0 = __builtin_bit_cast(short8, PB0);                                  \
    bs1 = __builtin_bit_cast(short8, PB1);                                  \
    bs2 = __builtin_bit_cast(short8, PB2);                                  \
    bs3 = __builtin_bit_cast(short8, PB3);                                  \
    MFMA_GRP(0, PA0);                                                       \
    WAITL(6); MFMA_GRP(1, PA1);                                             \
    WAITL(5); MFMA_GRP(2, f2);                                              \
    WAITL(4); MFMA_GRP(3, f3);                                              \
    WAITL(3); MFMA_GRP(4, f4);                                              \
    WAITL(2); MFMA_GRP(5, f5);                                              \
    WAITL(1); MFMA_GRP(6, f6);                                              \
    WAITL(0); MFMA_GRP(7, f7);                                              \
    __builtin_amdgcn_s_setprio(0);                                          \
    SB0;                                                                    \
    if (u_ + 1 < steps) {                                                   \
      const unsigned nA = ldsA0 + (unsigned)((u_ + 1) & 3) * 16384u + rowA; \
      const unsigned nB = ldsB0 + (unsigned)((u_ + 1) & 3) * 16384u + rowB; \
      DSR(NB0, nB, 0);                                                      \
      DSR(NB1, nB, 1024);                                                   \
      DSR(NB2, nB, 2048);                                                   \
      DSR(NB3, nB, 3072);                                                   \
      DSR(NA0, nA, 0);                                                      \
      DSR(NA1, nA, 1024);                                                   \
    }                                                                       \
    SB0;                                                                    \
    if (h3s) { asm volatile("s_waitcnt vmcnt(4)" ::: "memory"); }           \
    else     { asm volatile("s_waitcnt vmcnt(0)" ::: "memory"); }           \
    SB0;                                                                    \
    __builtin_amdgcn_s_barrier();                                           \
    SB0;                                                                    \
  }

  #pragma unroll 1
  for (int t = 0; t < steps; t += 2) {
    STEP_BODY(t,     pbE0, pbE1, pbE2, pbE3, paE0, paE1,
                     pbO0, pbO1, pbO2, pbO3, paO0, paO1);
    STEP_BODY(t + 1, pbO0, pbO1, pbO2, pbO3, paO0, paO1,
                     pbE0, pbE1, pbE2, pbE3, paE0, paE1);
  }

  // Full drain before epilogue (nothing may leak past kernel end).
  asm volatile("s_waitcnt vmcnt(0) lgkmcnt(0)" ::: "memory");
  __builtin_amdgcn_s_barrier();

  // Epilogue: C/D layout col=lane&15, row=quad*4+reg. Raw bf16 partials.
  #pragma unroll
  for (int j = 0; j < 4; ++j) {
    const int o = n0 + wn + j * 16 + l15;
    #pragma unroll
    for (int i = 0; i < 8; ++i) {
      #pragma unroll
      for (int r = 0; r < 4; ++r) {
        int m = m0 + wm + i * 16 + quad * 4 + r;
        partOut[(size_t)m * COUT + o] = f2bf(acc[i][j][r]);
      }
    }
  }
#undef STEP_BODY
#undef MFMA_GRP
}

// ---------------------------------------------------------------------------
// reduce1: sum 3 bf16 partial slices + bias, relu, cast bf16, scatter into
// padded P2 layout [t][6][16][16][1024] (interior only; halo pre-zeroed).
// ---------------------------------------------------------------------------
__global__ void reduce_conv1(const unsigned short* __restrict__ part,
                             const float* __restrict__ bias,
                             unsigned short* __restrict__ P2) {
  const int idx = blockIdx.x * 256 + threadIdx.x;
  const int m  = idx >> 8;
  const int o4 = (idx & 255) * 4;
  const size_t ss = (size_t)M_PAD * 1024;
  const size_t base = (size_t)m * 1024 + o4;
  ushort4v p0 = *(const ushort4v*)(part + base);
  ushort4v p1 = *(const ushort4v*)(part + ss + base);
  ushort4v p2 = *(const ushort4v*)(part + 2 * ss + base);
  ushort4v out;
  #pragma unroll
  for (int k = 0; k < 4; ++k) {
    float v = bf2f(p0[k]) + bf2f(p1[k]) + bf2f(p2[k]) + bias[o4 + k];
    out[k] = f2bf(v > 0.f ? v : 0.f);
  }
  int t = m / 784;  int r2 = m - t * 784;
  int d = r2 / 196; int r3 = r2 - d * 196;
  int h = r3 / 14;  int w = r3 - h * 14;
  size_t didx = (size_t)(((t * 6 + d + 1) * 16 + (h + 1)) * 16 + (w + 1)) * 1024 + o4;
  *(ushort4v*)(P2 + didx) = out;
}

// ---------------------------------------------------------------------------
// reduce2: sum 5 bf16 partial slices + bias, relu, cast bf16 -> h2 [6272][512].
// ---------------------------------------------------------------------------
__global__ void reduce_conv2(const unsigned short* __restrict__ part,
                             const float* __restrict__ bias,
                             unsigned short* __restrict__ h2) {
  const int idx = blockIdx.x * 256 + threadIdx.x;
  const int m  = idx >> 7;
  const int o4 = (idx & 127) * 4;
  const size_t base = (size_t)m * 512 + o4;
  const size_t ss = (size_t)M_PAD * 512;
  float acc[4];
  #pragma unroll
  for (int k = 0; k < 4; ++k) acc[k] = bias[o4 + k];
  #pragma unroll
  for (int s = 0; s < 5; ++s) {
    ushort4v p = *(const ushort4v*)(part + (size_t)s * ss + base);
    #pragma unroll
    for (int k = 0; k < 4; ++k) acc[k] += bf2f(p[k]);
  }
  ushort4v out;
  #pragma unroll
  for (int k = 0; k < 4; ++k) out[k] = f2bf(acc[k] > 0.f ? acc[k] : 0.f);
  *(ushort4v*)(h2 + base) = out;
}

// ---------------------------------------------------------------------------
// Max-pool, two-stage. h2 bf16 >= 0 -> bit pattern monotone -> max raw ushorts.
// ---------------------------------------------------------------------------
__global__ void pool1(const unsigned short* __restrict__ h2,
                      unsigned short* __restrict__ partial) {
  const int t = blockIdx.x / 28, ch = blockIdx.x % 28, o = threadIdx.x;
  const unsigned short* src = h2 + ((size_t)t * 784 + ch * 28) * 512 + o;
  unsigned short m = 0;
  #pragma unroll 4
  for (int i = 0; i < 28; ++i) { unsigned short v = src[(size_t)i * 512]; m = v > m ? v : m; }
  partial[((size_t)t * 28 + ch) * 512 + o] = m;
}

__global__ void pool2(const unsigned short* __restrict__ partial, float* __restrict__ pooled) {
  const int t = blockIdx.x, o = threadIdx.x;
  const unsigned short* src = partial + (size_t)t * 28 * 512 + o;
  unsigned short m = 0;
  #pragma unroll 4
  for (int i = 0; i < 28; ++i) { unsigned short v = src[(size_t)i * 512]; m = v > m ? v : m; }
  pooled[t * 512 + o] = bf2f(m);
}

// ---------------------------------------------------------------------------
// Tiny MLP, fp32. Block per t, 512 threads.
// ---------------------------------------------------------------------------
__global__ void mlp_kernel(const float* __restrict__ pooled,
                           const float* __restrict__ w1, const float* __restrict__ b1,
                           const float* __restrict__ w2, const float* __restrict__ b2,
                           const float* __restrict__ w3, const float* __restrict__ b3,
                           float* __restrict__ out) {
  const int t = blockIdx.x, j = threadIdx.x;
  __shared__ float xa[512], xb[512];
  xa[j] = pooled[t * 512 + j];
  __syncthreads();
  {
    const float4* wr = (const float4*)(w1 + (size_t)j * 512);
    float s = b1[j];
    #pragma unroll 4
    for (int k = 0; k < 128; ++k) {
      float4 wv = wr[k];
      s += wv.x * xa[4*k] + wv.y * xa[4*k+1] + wv.z * xa[4*k+2] + wv.w * xa[4*k+3];
    }
    xb[j] = fmaxf(s, 0.f);
  }
  __syncthreads();
  {
    const float4* wr = (const float4*)(w2 + (size_t)j * 512);
    float s = b2[j];
    #pragma unroll 4
    for (int k = 0; k < 128; ++k) {
      float4 wv = wr[k];
      s += wv.x * xb[4*k] + wv.y * xb[4*k+1] + wv.z * xb[4*k+2] + wv.w * xb[4*k+3];
    }
    xa[j] = fmaxf(s, 0.f);
  }
  __syncthreads();
  if (j < 128) {
    const float4* wr = (const float4*)(w3 + (size_t)j * 512);
    float s = b3[j];
    #pragma unroll 4
    for (int k = 0; k < 128; ++k) {
      float4 wv = wr[k];
      s += wv.x * xa[4*k] + wv.y * xa[4*k+1] + wv.z * xa[4*k+2] + wv.w * xa[4*k+3];
    }
    out[t * 128 + j] = fmaxf(s, 0.f);
  }
}

// ---------------------------------------------------------------------------
// Host schedule: per block (m-tile x2, n-tile, K-slice z, tap range).
// conv1: ns = nv/9 -> every block exactly 9 valid taps (uniform, 288 steps).
// conv2: ns = 5 (27 taps) or 4 (18 taps).  Grid <= 256 at 1 block/CU;
// XCD-grouped interleave (block g -> XCD g%8 contiguous chunk).
// ---------------------------------------------------------------------------
static int build_sched(bool conv1, unsigned int* out) {
  const int nt = conv1 ? 4 : 2;
  unsigned int L[256];
  int cnt = 0;
  for (int n = 0; n < nt; ++n) {
    for (int x2 = 0; x2 < 25; ++x2) {
      const int m0 = x2 * 256;
      bool kdv[3] = {false, false, false};
      const int cA = m0 / 196;
      int cB = (m0 + 255) / 196; if (cB > 31) cB = 31;
      for (int c = cA; c <= cB; ++c) {
        int t = c >> 2, d = c & 3;
        for (int kd = 0; kd < 3; ++kd) {
          int s = d + kd;
          bool ok = (s >= 1 && s <= 4);
          if (conv1) ok = ok && (s >= 5 - t);
          kdv[kd] = kdv[kd] || ok;
        }
      }
      int vt[27], nv = 0;
      for (int tp = 0; tp < 27; ++tp) if (kdv[tp / 9]) vt[nv++] = tp;
      if (!nv) continue;
      const int ns = conv1 ? (nv / 9) : ((nv == 27) ? 5 : 4);
      for (int s = 0; s < ns; ++s) {
        int b0 = nv * s / ns, b1 = nv * (s + 1) / ns;
        int tp0 = vt[b0], tp1 = vt[b1 - 1] + 1;
        L[cnt++] = (unsigned int)(x2 | (n << 5) | (s << 7) | (tp0 << 10) | (tp1 << 15));
      }
    }
  }
  const int q = cnt / 8, r = cnt % 8;
  int pos = 0;
  for (int b = 0; b < 8; ++b) {
    const int nb = q + (b < r ? 1 : 0);
    for (int j = 0; j < nb; ++j) out[j * 8 + b] = L[pos++];
  }
  return cnt;
}

// ---------------------------------------------------------------------------
// Workspace layout (bytes) — total 122,685,440:
//   P12 (P1/P2, 51 slots incl t=8 pad) @ 0         : 26,738,688
//   W1t                       @ 26,738,688         : 56,623,104  (dead after gemm1)
//     W2t  (aliases W1t)      @ 26,738,688         : 28,311,552  (built after gemm1)
//     h2                      @ 55,050,240         :  6,422,528
//     pooled                  @ 61,472,768         :     16,384
//     ppart                   @ 61,489,152         :    229,376
//   part                      @ 83,361,792         : 39,321,600  (conv1 3x6400x1024,
//                                                    conv2 5x6400x512 = 32,768,000)
//   sched1 / sched2           @ 122,683,392 / 122,684,416 : 1,024 each
// ---------------------------------------------------------------------------
extern "C" void kernel_launch(void* const* d_in, const int* in_sizes, int n_in,
                              void* d_out, int out_size, void* d_ws, size_t ws_size,
                              hipStream_t stream) {
  const float* videos = (const float*)d_in[0];
  const float* c1w = (const float*)d_in[1];
  const float* c1b = (const float*)d_in[2];
  const float* c2w = (const float*)d_in[3];
  const float* c2b = (const float*)d_in[4];
  const float* l1w = (const float*)d_in[5];
  const float* l1b = (const float*)d_in[6];
  const float* l2w = (const float*)d_in[7];
  const float* l2b = (const float*)d_in[8];
  const float* l3w = (const float*)d_in[9];
  const float* l3b = (const float*)d_in[10];

  char* ws = (char*)d_ws;
  unsigned short* P12   = (unsigned short*)(ws);
  unsigned short* W1t   = (unsigned short*)(ws + 26738688);
  unsigned short* W2t   = (unsigned short*)(ws + 26738688);   // aliases W1t
  unsigned short* h2    = (unsigned short*)(ws + 55050240);
  float*          pooled= (float*)(ws + 61472768);
  unsigned short* ppart = (unsigned short*)(ws + 61489152);
  unsigned short* part  = (unsigned short*)(ws + 83361792);
  unsigned int* dsched1 = (unsigned int*)(ws + 122683392);
  unsigned int* dsched2 = (unsigned int*)(ws + 122684416);
  float* out = (float*)d_out;

  // Host scheds: static so captured memcpy sources persist across graph replays.
  static unsigned int s1h[256], s2h[256];
  const int n1 = build_sched(true,  s1h);
  const int n2 = build_sched(false, s2h);
  hipMemcpyAsync(dsched1, s1h, sizeof(s1h), hipMemcpyHostToDevice, stream);
  hipMemcpyAsync(dsched2, s2h, sizeof(s2h), hipMemcpyHostToDevice, stream);

  // Zero padded activation buffer (halo + unused windows + t=8 pad slots).
  hipMemsetAsync(ws, 0, 26738688, stream);
  // Zero conv1 partials (empty m-tiles + unused slices).
  hipMemsetAsync(part, 0, 39321600, stream);

  wtrans<<<4096, 256, 0, stream>>>(c1w, W1t, 1024 * 1024);
  build_P1<<<dim3(8, 16), 256, 0, stream>>>(videos, P12);

  conv_gemm<1024, true ><<<n1, 512, 0, stream>>>(P12, W1t, dsched1, part);

  // W2t overwrites W1t — only after conv_gemm1 is done (stream order).
  wtrans<<<2048, 256, 0, stream>>>(c2w, W2t, 512 * 1024);
  reduce_conv1<<<6272, 256, 0, stream>>>(part, c1b, P12);
  // conv2: x2=24 blocks have 4 slices; zero z=4 rows 6144.. (after reduce1!).
  hipMemsetAsync((char*)part + 32505856, 0, 262144, stream);

  conv_gemm<512, false><<<n2, 512, 0, stream>>>(P12, W2t, dsched2, part);
  reduce_conv2<<<3136, 256, 0, stream>>>(part, c2b, h2);

  pool1<<<224, 512, 0, stream>>>(h2, ppart);
  pool2<<<8, 512, 0, stream>>>(ppart, pooled);
  mlp_kernel<<<8, 512, 0, stream>>>(pooled, l1w, l1b, l2w, l2b, l3w, l3b, out);
}

// Round 10
// 746.076 us; speedup vs baseline: 1.2363x; 1.0026x over previous
//
#include <hip/hip_runtime.h>

typedef __attribute__((ext_vector_type(8))) short short8;
typedef __attribute__((ext_vector_type(4))) int int4v;
typedef __attribute__((ext_vector_type(4))) float floatx4;
typedef __attribute__((ext_vector_type(4))) unsigned short ushort4v;

#define DEV __device__ __forceinline__

constexpr int M_TOT = 6272;   // 8 * 784 real output positions
constexpr int M_PAD = 6400;   // padded to 25*256 (pad rows read zeroed P slots)

DEV void async_ld16(const void* g, void* l) {
  __builtin_amdgcn_global_load_lds(
      (const __attribute__((address_space(1))) unsigned int*)g,
      (__attribute__((address_space(3))) unsigned int*)l,
      16, 0, 0);
}

DEV unsigned short f2bf(float x) {
  union { float f; unsigned int u; } v; v.f = x;
  unsigned int u = v.u;
  u += 0x7FFFu + ((u >> 16) & 1u);   // round-to-nearest-even
  return (unsigned short)(u >> 16);
}

DEV float bf2f(unsigned short s) {
  union { unsigned int u; float f; } v; v.u = ((unsigned int)s) << 16;
  return v.f;
}

// ---------------------------------------------------------------------------
// Compile-time schedule + slice-count tables (pure functions of constants).
// Removes the runtime memcpys AND the 39 MB part memset (reducers sum only
// slices the schedule actually writes).
// ---------------------------------------------------------------------------
struct Sched { unsigned v[256]; int n; };
struct NsTab { unsigned char v[25]; };

constexpr void cell_kdv(bool conv1, int x2, bool kdv[3]) {
  const int m0 = x2 * 256;
  const int cA = m0 / 196;
  int cB = (m0 + 255) / 196; if (cB > 31) cB = 31;
  for (int c = cA; c <= cB; ++c) {
    int t = c >> 2, d = c & 3;
    for (int kd = 0; kd < 3; ++kd) {
      int s = d + kd;
      bool ok = (s >= 1 && s <= 4);
      if (conv1) ok = ok && (s >= 5 - t);
      kdv[kd] = kdv[kd] || ok;
    }
  }
}

constexpr Sched mk_sched(bool conv1) {
  Sched out{};
  const int nt = conv1 ? 4 : 2;
  unsigned L[256] = {};
  int cnt = 0;
  for (int n = 0; n < nt; ++n) {
    for (int x2 = 0; x2 < 25; ++x2) {
      bool kdv[3] = {false, false, false};
      cell_kdv(conv1, x2, kdv);
      int vt[27] = {}; int nv = 0;
      for (int tp = 0; tp < 27; ++tp) if (kdv[tp / 9]) vt[nv++] = tp;
      if (!nv) continue;
      const int ns = conv1 ? (nv / 9) : ((nv == 27) ? 5 : 4);
      for (int s = 0; s < ns; ++s) {
        int b0 = nv * s / ns, b1 = nv * (s + 1) / ns;
        int tp0 = vt[b0], tp1 = vt[b1 - 1] + 1;
        L[cnt++] = (unsigned)(x2 | (n << 5) | (s << 7) | (tp0 << 10) | (tp1 << 15));
      }
    }
  }
  // XCD-grouped interleave: block g -> XCD g%8 contiguous chunk.
  const int q = cnt / 8, r = cnt % 8;
  int pos = 0;
  for (int b = 0; b < 8; ++b) {
    const int nb = q + (b < r ? 1 : 0);
    for (int j = 0; j < nb; ++j) out.v[j * 8 + b] = L[pos++];
  }
  out.n = cnt;
  return out;
}

constexpr NsTab mk_ns(bool conv1) {
  NsTab t{};
  for (int x2 = 0; x2 < 25; ++x2) {
    bool kdv[3] = {false, false, false};
    cell_kdv(conv1, x2, kdv);
    int nv = 0;
    for (int tp = 0; tp < 27; ++tp) if (kdv[tp / 9]) ++nv;
    t.v[x2] = (nv == 0) ? 0 : (unsigned char)(conv1 ? (nv / 9) : ((nv == 27) ? 5 : 4));
  }
  return t;
}

constexpr Sched S1h = mk_sched(true);    // host: grid sizes
constexpr Sched S2h = mk_sched(false);
__constant__ Sched dS1 = mk_sched(true);  // device copies
__constant__ Sched dS2 = mk_sched(false);
__constant__ NsTab dNS1 = mk_ns(true);
__constant__ NsTab dNS2 = mk_ns(false);

// ---------------------------------------------------------------------------
// Weight transform: conv_w fp32 [O][C][3][3][3] -> bf16 [tap][o][c]  (B^T).
// ---------------------------------------------------------------------------
__global__ void wtrans(const float* __restrict__ w, unsigned short* __restrict__ wt,
                       int total /* = O*C, multiple of 256 */) {
  __shared__ unsigned short l[256 * 27];
  const int tid  = threadIdx.x;
  const int base = blockIdx.x * 256;
  #pragma unroll 1
  for (int j = tid; j < 256 * 27; j += 256)
    l[j] = f2bf(w[(size_t)base * 27 + j]);
  __syncthreads();
  #pragma unroll 1
  for (int tap = 0; tap < 27; ++tap)
    wt[(size_t)tap * total + base + tid] = l[tid * 27 + tap];
}

// ---------------------------------------------------------------------------
// Build P1: videos fp32 [8][1024][14][14] -> P1 bf16 [t=8][s=6][16][16][1024]
// P1[t][s][h+1][w+1][c] = videos[t-5+s][c][h][w] for s in 1..4 (else zero).
// ---------------------------------------------------------------------------
__global__ void build_P1(const float* __restrict__ videos, unsigned short* __restrict__ P1) {
  const int f  = blockIdx.x;
  const int c0 = blockIdx.y * 64;
  const int tid = threadIdx.x;
  __shared__ unsigned short tile[64][196];

  #pragma unroll 1
  for (int it = 0; it < 49; ++it) {       // 49*256 = 64*196 exactly
    int idx = it * 256 + tid;
    int c = idx / 196, r = idx - c * 196;
    tile[c][r] = f2bf(videos[(size_t)(f * 1024 + c0 + c) * 196 + r]);
  }
  __syncthreads();

  const int c   = tid & 63;
  const int hwq = tid >> 6;
  #pragma unroll 1
  for (int s = 1; s <= 4; ++s) {
    int t = f + 5 - s;
    if (t > 7) continue;
    unsigned short* dst = P1 + (size_t)(t * 6 + s) * 256 * 1024 + (size_t)c0;
    #pragma unroll 1
    for (int it = 0; it < 49; ++it) {
      int hw = it * 4 + hwq;
      int h = hw / 14, w = hw - h * 14;
      dst[(size_t)((h + 1) * 16 + (w + 1)) * 1024 + c] = tile[c][hw];
    }
  }
}

// Pinned-order LDS read (issue order = program order among volatile asm).
#define DSR(dst, addr, off) \
  asm volatile("ds_read_b128 %0, %1 offset:" #off : "=&v"(dst) : "v"(addr))
#define WAITL(n) \
  asm volatile("s_waitcnt lgkmcnt(" #n ")" ::: "memory"); \
  __builtin_amdgcn_sched_barrier(0)
#define SB0 __builtin_amdgcn_sched_barrier(0)

// ---------------------------------------------------------------------------
// R14: R13's pre-read ladder pipeline (best: 254 us, MfmaUtil 48) with the
// staging address path made INCREMENTAL: pa/pb pointers advance by +64 B per
// step; full tap-base recompute (div 9/3, 64-bit adds) only every 32 steps.
// Cuts ~25 VALU ops/step/wave (VALUBusy 18.6% -> ~15%).  Schedule comes from
// __constant__ (no memcpys).  Everything else identical to R13:
//  - 4-slot LDS quad buffer, stage t+3 into (t-1)&3, boundary vmcnt(4)
//  - cross-step pre-read of b0..b3,a0,a1 into E/O register banks
//  - counted-lgkm ladder, ONE barrier per step, setprio on MFMA
// ---------------------------------------------------------------------------
template <int COUT, bool TCOND>
__global__ __launch_bounds__(512, 2) void conv_gemm(
    const unsigned short* __restrict__ P,
    const unsigned short* __restrict__ Wt,
    unsigned short* __restrict__ part)
{
  constexpr int CIN = 1024;
  __shared__ short lA[4][8192];   // 4 slots x 16 KiB  (256 rows x 32 k)
  __shared__ short lB[4][8192];
  const int tid  = threadIdx.x;
  const int wave = tid >> 6;
  const int lane = tid & 63;

  const unsigned int e = (TCOND ? dS1 : dS2).v[blockIdx.x];
  const int x2   = e & 31;
  const int nidx = (e >> 5) & 3;
  const int zs   = (e >> 7) & 7;
  const int tap0 = (e >> 10) & 31;
  const int tap1 = (e >> 15) & 31;
  const int m0 = x2 * 256;
  const int n0 = nidx * 256;
  unsigned short* partOut = part + (size_t)zs * M_PAD * COUT;

  // Tile-level depth-tap validity over spanned REAL (t,d) cells (pad excluded).
  bool kdv[3] = {false, false, false};
  {
    const int cA = m0 / 196;
    int cB = (m0 + 255) / 196; if (cB > 31) cB = 31;
    for (int c = cA; c <= cB; ++c) {
      int t = c >> 2, d = c & 3;
      #pragma unroll
      for (int kd = 0; kd < 3; ++kd) {
        int s = d + kd;
        bool ok = (s >= 1) && (s <= 4);
        if (TCOND) ok = ok && (s >= 5 - t);
        kdv[kd] = kdv[kd] || ok;
      }
    }
  }

  // Staging geometry: thread covers (row = tid>>2 within 128-row half,
  // seg = tid&3); global source pre-swizzled: chunk (tid&3) ^ ((row>>1)&3).
  const int arow = tid >> 2;
  const int aswz = (((tid & 3) ^ ((arow >> 1) & 3)) << 4);
  int aG[2], bG[2];
  #pragma unroll
  for (int q = 0; q < 2; ++q) {
    int m = m0 + q * 128 + arow;
    int t = m / 784;  int r2 = m - t * 784;
    int d = r2 / 196; int r3 = r2 - d * 196;
    int h = r3 / 14;  int w = r3 - h * 14;
    aG[q] = ((((t * 6 + d) * 16 + h) * 16 + w) * CIN) * 2 + aswz;
    bG[q] = (n0 + q * 128 + arow) * (CIN * 2) + aswz;
  }

  // Step stream: 32 K-steps per valid tap (steps = nvt*32, even, >= 32).
  int nvt = 0;
  for (int tp = tap0; tp < tap1; ++tp) if (kdv[tp / 9]) ++nvt;
  const int steps = nvt * 32;
  const char* Pb = (const char*)P;
  const char* Wb = (const char*)Wt;

  // Incremental staging pointers (R14): recompute only at tap boundaries.
  int tapS = tap0;
  while (tapS < tap1 && !kdv[tapS / 9]) ++tapS;
  int scnt = 0;
  const char *pa0 = nullptr, *pa1 = nullptr, *pb0 = nullptr, *pb1 = nullptr;
  auto tapBase = [&]() {
    const int kd = tapS / 9, rm = tapS - kd * 9;
    const int kh = rm / 3, kw = rm - kh * 3;
    const int tA = ((((kd * 16) + kh) * 16 + kw) * CIN) * 2;
    const int tB = tapS * (COUT * CIN * 2);
    pa0 = Pb + aG[0] + tA;  pa1 = Pb + aG[1] + tA;
    pb0 = Wb + bG[0] + tB;  pb1 = Wb + bG[1] + tB;
  };
  auto advS = [&]() {
    if (++scnt == 32) {
      scnt = 0;
      do { ++tapS; } while (tapS < tap1 && !kdv[tapS / 9]);
      if (tapS < tap1) tapBase();
    } else {
      pa0 += 64; pa1 += 64; pb0 += 64; pb1 += 64;
    }
  };
  tapBase();

  char* lAc = (char*)&lA[0][0];
  char* lBc = (char*)&lB[0][0];
  const unsigned ldsA0 =
      (unsigned)(size_t)(__attribute__((address_space(3))) char*)lAc;
  const unsigned ldsB0 =
      (unsigned)(size_t)(__attribute__((address_space(3))) char*)lBc;

  // Prologue: stage slots 0,1,2 (12 vm loads); vmcnt(4) retires slots 0,1
  // (keeps stage-2 in flight); barrier.
  #pragma unroll 1
  for (int s = 0; s < 3; ++s) {
    char* dA = lAc + s * 16384;
    char* dB = lBc + s * 16384;
    async_ld16(pa0, dA + tid * 16);
    async_ld16(pb0, dB + tid * 16);
    async_ld16(pa1, dA + 8192 + tid * 16);
    async_ld16(pb1, dB + 8192 + tid * 16);
    advS();
  }
  asm volatile("s_waitcnt vmcnt(4)" ::: "memory");
  __builtin_amdgcn_s_barrier();
  SB0;

  const int wm   = (wave >> 2) * 128;
  const int wn   = (wave & 3) * 64;
  const int quad = lane >> 4;
  const int l15  = lane & 15;
  const int segc = ((quad ^ ((l15 >> 1) & 3)) << 4);
  const unsigned rowA = ((unsigned)(wm + l15) << 6) + segc;   // + i*1024 imm
  const unsigned rowB = ((unsigned)(wn + l15) << 6) + segc;   // + j*1024 imm

  floatx4 acc[8][4];
  const floatx4 zero4 = {0.f, 0.f, 0.f, 0.f};
  #pragma unroll
  for (int i = 0; i < 8; ++i)
    #pragma unroll
    for (int j = 0; j < 4; ++j) acc[i][j] = zero4;

  // Pre-read banks (E: even steps, O: odd steps).  Constant indices only.
  int4v pbE0, pbE1, pbE2, pbE3, paE0, paE1;
  int4v pbO0, pbO1, pbO2, pbO3, paO0, paO1;

  // Prologue pre-read for step 0 (slot 0 resident after vmcnt(4)+barrier).
  {
    const unsigned aB = ldsA0 + rowA;
    const unsigned bB = ldsB0 + rowB;
    DSR(pbE0, bB, 0);
    DSR(pbE1, bB, 1024);
    DSR(pbE2, bB, 2048);
    DSR(pbE3, bB, 3072);
    DSR(paE0, aB, 0);
    DSR(paE1, aB, 1024);
  }
  SB0;

#define MFMA_GRP(ACCI, AV)                                                  \
  {                                                                         \
    short8 a_ = __builtin_bit_cast(short8, AV);                             \
    acc[ACCI][0] = __builtin_amdgcn_mfma_f32_16x16x32_bf16(a_, bs0, acc[ACCI][0], 0, 0, 0); \
    acc[ACCI][1] = __builtin_amdgcn_mfma_f32_16x16x32_bf16(a_, bs1, acc[ACCI][1], 0, 0, 0); \
    acc[ACCI][2] = __builtin_amdgcn_mfma_f32_16x16x32_bf16(a_, bs2, acc[ACCI][2], 0, 0, 0); \
    acc[ACCI][3] = __builtin_amdgcn_mfma_f32_16x16x32_bf16(a_, bs3, acc[ACCI][3], 0, 0, 0); \
  }

#define STEP_BODY(U, PB0, PB1, PB2, PB3, PA0, PA1, NB0, NB1, NB2, NB3, NA0, NA1) \
  {                                                                         \
    const int u_ = (U);                                                     \
    const bool h3s = (u_ + 3 < steps);                                      \
    const unsigned aB = ldsA0 + (unsigned)(u_ & 3) * 16384u + rowA;         \
    int4v f2, f3, f4, f5, f6, f7;                                           \
    DSR(f2, aB, 2048);                                                      \
    DSR(f3, aB, 3072);                                                      \
    DSR(f4, aB, 4096);                                                      \
    DSR(f5, aB, 5120);                                                      \
    DSR(f6, aB, 6144);                                                      \
    DSR(f7, aB, 7168);                                                      \
    SB0;                                                                    \
    if (h3s) {                                                              \
      char* dA = lAc + ((u_ + 3) & 3) * 16384;                              \
      char* dB = lBc + ((u_ + 3) & 3) * 16384;                              \
      async_ld16(pa0, dA + tid * 16);                                       \
      async_ld16(pb0, dB + tid * 16);                                       \
      async_ld16(pa1, dA + 8192 + tid * 16);                                \
      async_ld16(pb1, dB + 8192 + tid * 16);                                \
      advS();                                                               \
    }                                                                       \
    SB0;                                                                    \
    __builtin_amdgcn_s_setprio(1);                                          \
    short8 bs0, bs1, bs2, bs3;                                              \
    WAITL(7);                                                               \
    bs0 = __builtin_bit_cast(short8, PB0);                                  \
    bs1 = __builtin_bit_cast(short8, PB1);                                  \
    bs2 = __builtin_bit_cast(short8, PB2);                                  \
    bs3 = __builtin_bit_cast(short8, PB3);                                  \
    MFMA_GRP(0, PA0);                                                       \
    WAITL(6); MFMA_GRP(1, PA1);                                             \
    WAITL(5); MFMA_GRP(2, f2);                                              \
    WAITL(4); MFMA_GRP(3, f3);                                              \
    WAITL(3); MFMA_GRP(4, f4);                                              \
    WAITL(2); MFMA_GRP(5, f5);                                              \
    WAITL(1); MFMA_GRP(6, f6);                                              \
    WAITL(0); MFMA_GRP(7, f7);                                              \
    __builtin_amdgcn_s_setprio(0);                                          \
    SB0;                                                                    \
    if (u_ + 1 < steps) {                                                   \
      const unsigned nA = ldsA0 + (unsigned)((u_ + 1) & 3) * 16384u + rowA; \
      const unsigned nB = ldsB0 + (unsigned)((u_ + 1) & 3) * 16384u + rowB; \
      DSR(NB0, nB, 0);                                                      \
      DSR(NB1, nB, 1024);                                                   \
      DSR(NB2, nB, 2048);                                                   \
      DSR(NB3, nB, 3072);                                                   \
      DSR(NA0, nA, 0);                                                      \
      DSR(NA1, nA, 1024);                                                   \
    }                                                                       \
    SB0;                                                                    \
    if (h3s) { asm volatile("s_waitcnt vmcnt(4)" ::: "memory"); }           \
    else     { asm volatile("s_waitcnt vmcnt(0)" ::: "memory"); }           \
    SB0;                                                                    \
    __builtin_amdgcn_s_barrier();                                           \
    SB0;                                                                    \
  }

  #pragma unroll 1
  for (int t = 0; t < steps; t += 2) {
    STEP_BODY(t,     pbE0, pbE1, pbE2, pbE3, paE0, paE1,
                     pbO0, pbO1, pbO2, pbO3, paO0, paO1);
    STEP_BODY(t + 1, pbO0, pbO1, pbO2, pbO3, paO0, paO1,
                     pbE0, pbE1, pbE2, pbE3, paE0, paE1);
  }

  // Full drain before epilogue (nothing may leak past kernel end).
  asm volatile("s_waitcnt vmcnt(0) lgkmcnt(0)" ::: "memory");
  __builtin_amdgcn_s_barrier();

  // Epilogue: C/D layout col=lane&15, row=quad*4+reg. Raw bf16 partials.
  #pragma unroll
  for (int j = 0; j < 4; ++j) {
    const int o = n0 + wn + j * 16 + l15;
    #pragma unroll
    for (int i = 0; i < 8; ++i) {
      #pragma unroll
      for (int r = 0; r < 4; ++r) {
        int m = m0 + wm + i * 16 + quad * 4 + r;
        partOut[(size_t)m * COUT + o] = f2bf(acc[i][j][r]);
      }
    }
  }
#undef STEP_BODY
#undef MFMA_GRP
}

// ---------------------------------------------------------------------------
// reduce1: sum the ns(x2) written bf16 partial slices + bias, relu, cast
// bf16, scatter into padded P2 layout (interior only; halo pre-zeroed).
// ns from constexpr table -> NO part memset needed (unwritten slices never
// read; ns==0 regions output relu(bias), matching conv-of-zero + bias).
// ---------------------------------------------------------------------------
__global__ void reduce_conv1(const unsigned short* __restrict__ part,
                             const float* __restrict__ bias,
                             unsigned short* __restrict__ P2) {
  const int m  = blockIdx.x;              // one m per block (256 threads)
  const int o4 = threadIdx.x * 4;
  const int ns = dNS1.v[m >> 8];
  const size_t ss = (size_t)M_PAD * 1024;
  const size_t base = (size_t)m * 1024 + o4;
  float v[4];
  #pragma unroll
  for (int k = 0; k < 4; ++k) v[k] = bias[o4 + k];
  #pragma unroll 1
  for (int z = 0; z < ns; ++z) {
    ushort4v p = *(const ushort4v*)(part + (size_t)z * ss + base);
    #pragma unroll
    for (int k = 0; k < 4; ++k) v[k] += bf2f(p[k]);
  }
  ushort4v out;
  #pragma unroll
  for (int k = 0; k < 4; ++k) out[k] = f2bf(v[k] > 0.f ? v[k] : 0.f);
  int t = m / 784;  int r2 = m - t * 784;
  int d = r2 / 196; int r3 = r2 - d * 196;
  int h = r3 / 14;  int w = r3 - h * 14;
  size_t didx = (size_t)(((t * 6 + d + 1) * 16 + (h + 1)) * 16 + (w + 1)) * 1024 + o4;
  *(ushort4v*)(P2 + didx) = out;
}

// ---------------------------------------------------------------------------
// reduce2: sum ns2(x2) bf16 partial slices + bias, relu -> h2 [6272][512].
// ---------------------------------------------------------------------------
__global__ void reduce_conv2(const unsigned short* __restrict__ part,
                             const float* __restrict__ bias,
                             unsigned short* __restrict__ h2) {
  const int idx = blockIdx.x * 256 + threadIdx.x;
  const int m  = idx >> 7;
  const int o4 = (idx & 127) * 4;
  const int ns = dNS2.v[m >> 8];
  const size_t base = (size_t)m * 512 + o4;
  const size_t ss = (size_t)M_PAD * 512;
  float acc[4];
  #pragma unroll
  for (int k = 0; k < 4; ++k) acc[k] = bias[o4 + k];
  #pragma unroll 1
  for (int s = 0; s < ns; ++s) {
    ushort4v p = *(const ushort4v*)(part + (size_t)s * ss + base);
    #pragma unroll
    for (int k = 0; k < 4; ++k) acc[k] += bf2f(p[k]);
  }
  ushort4v out;
  #pragma unroll
  for (int k = 0; k < 4; ++k) out[k] = f2bf(acc[k] > 0.f ? acc[k] : 0.f);
  *(ushort4v*)(h2 + base) = out;
}

// ---------------------------------------------------------------------------
// Max-pool stage 1. h2 bf16 >= 0 -> bit pattern monotone -> max raw ushorts.
// ---------------------------------------------------------------------------
__global__ void pool1(const unsigned short* __restrict__ h2,
                      unsigned short* __restrict__ partial) {
  const int t = blockIdx.x / 28, ch = blockIdx.x % 28, o = threadIdx.x;
  const unsigned short* src = h2 + ((size_t)t * 784 + ch * 28) * 512 + o;
  unsigned short m = 0;
  #pragma unroll 4
  for (int i = 0; i < 28; ++i) { unsigned short v = src[(size_t)i * 512]; m = v > m ? v : m; }
  partial[((size_t)t * 28 + ch) * 512 + o] = m;
}

// ---------------------------------------------------------------------------
// Pool stage 2 fused into the tiny MLP.  Block per t, 512 threads.
// ---------------------------------------------------------------------------
__global__ void mlp_kernel(const unsigned short* __restrict__ ppart,
                           const float* __restrict__ w1, const float* __restrict__ b1,
                           const float* __restrict__ w2, const float* __restrict__ b2,
                           const float* __restrict__ w3, const float* __restrict__ b3,
                           float* __restrict__ out) {
  const int t = blockIdx.x, j = threadIdx.x;
  __shared__ float xa[512], xb[512];
  {
    const unsigned short* src = ppart + (size_t)t * 28 * 512 + j;
    unsigned short m = 0;
    #pragma unroll 4
    for (int i = 0; i < 28; ++i) { unsigned short v = src[(size_t)i * 512]; m = v > m ? v : m; }
    xa[j] = bf2f(m);
  }
  __syncthreads();
  {
    const float4* wr = (const float4*)(w1 + (size_t)j * 512);
    float s = b1[j];
    #pragma unroll 4
    for (int k = 0; k < 128; ++k) {
      float4 wv = wr[k];
      s += wv.x * xa[4*k] + wv.y * xa[4*k+1] + wv.z * xa[4*k+2] + wv.w * xa[4*k+3];
    }
    xb[j] = fmaxf(s, 0.f);
  }
  __syncthreads();
  {
    const float4* wr = (const float4*)(w2 + (size_t)j * 512);
    float s = b2[j];
    #pragma unroll 4
    for (int k = 0; k < 128; ++k) {
      float4 wv = wr[k];
      s += wv.x * xb[4*k] + wv.y * xb[4*k+1] + wv.z * xb[4*k+2] + wv.w * xb[4*k+3];
    }
    xa[j] = fmaxf(s, 0.f);
  }
  __syncthreads();
  if (j < 128) {
    const float4* wr = (const float4*)(w3 + (size_t)j * 512);
    float s = b3[j];
    #pragma unroll 4
    for (int k = 0; k < 128; ++k) {
      float4 wv = wr[k];
      s += wv.x * xa[4*k] + wv.y * xa[4*k+1] + wv.z * xa[4*k+2] + wv.w * xa[4*k+3];
    }
    out[t * 128 + j] = fmaxf(s, 0.f);
  }
}

// ---------------------------------------------------------------------------
// Workspace layout (bytes) — total 122,683,392:
//   P12 (P1/P2, 51 slots incl t=8 pad) @ 0         : 26,738,688
//   W1t                       @ 26,738,688         : 56,623,104  (dead after gemm1)
//     W2t  (aliases W1t)      @ 26,738,688         : 28,311,552  (built after gemm1)
//     h2                      @ 55,050,240         :  6,422,528
//     ppart                   @ 61,489,152         :    229,376
//   part                      @ 83,361,792         : 39,321,600
// Dispatches: 1 memset + 9 kernels (was 15 incl. 2 memcpys + 3 memsets).
// ---------------------------------------------------------------------------
extern "C" void kernel_launch(void* const* d_in, const int* in_sizes, int n_in,
                              void* d_out, int out_size, void* d_ws, size_t ws_size,
                              hipStream_t stream) {
  const float* videos = (const float*)d_in[0];
  const float* c1w = (const float*)d_in[1];
  const float* c1b = (const float*)d_in[2];
  const float* c2w = (const float*)d_in[3];
  const float* c2b = (const float*)d_in[4];
  const float* l1w = (const float*)d_in[5];
  const float* l1b = (const float*)d_in[6];
  const float* l2w = (const float*)d_in[7];
  const float* l2b = (const float*)d_in[8];
  const float* l3w = (const float*)d_in[9];
  const float* l3b = (const float*)d_in[10];

  char* ws = (char*)d_ws;
  unsigned short* P12   = (unsigned short*)(ws);
  unsigned short* W1t   = (unsigned short*)(ws + 26738688);
  unsigned short* W2t   = (unsigned short*)(ws + 26738688);   // aliases W1t
  unsigned short* h2    = (unsigned short*)(ws + 55050240);
  unsigned short* ppart = (unsigned short*)(ws + 61489152);
  unsigned short* part  = (unsigned short*)(ws + 83361792);
  float* out = (float*)d_out;

  // Zero padded activation buffer (halo + unused windows + t=8 pad slots).
  hipMemsetAsync(ws, 0, 26738688, stream);

  wtrans<<<4096, 256, 0, stream>>>(c1w, W1t, 1024 * 1024);
  build_P1<<<dim3(8, 16), 256, 0, stream>>>(videos, P12);

  conv_gemm<1024, true ><<<S1h.n, 512, 0, stream>>>(P12, W1t, part);

  // W2t overwrites W1t — only after conv_gemm1 is done (stream order).
  wtrans<<<2048, 256, 0, stream>>>(c2w, W2t, 512 * 1024);
  reduce_conv1<<<6272, 256, 0, stream>>>(part, c1b, P12);

  conv_gemm<512, false><<<S2h.n, 512, 0, stream>>>(P12, W2t, part);
  reduce_conv2<<<3136, 256, 0, stream>>>(part, c2b, h2);

  pool1<<<224, 512, 0, stream>>>(h2, ppart);
  mlp_kernel<<<8, 512, 0, stream>>>(ppart, l1w, l1b, l2w, l2b, l3w, l3b, out);
}

// Round 11
// 689.600 us; speedup vs baseline: 1.3375x; 1.0819x over previous
//
#include <hip/hip_runtime.h>

typedef __attribute__((ext_vector_type(8))) short short8;
typedef __attribute__((ext_vector_type(4))) int int4v;
typedef __attribute__((ext_vector_type(4))) float floatx4;
typedef __attribute__((ext_vector_type(4))) unsigned short ushort4v;

#define DEV __device__ __forceinline__

constexpr int M_TOT = 6272;   // 8 * 784 real output positions
constexpr int M_PAD = 6400;   // padded to 25*256 (pad rows read zeroed P slots)

DEV void async_ld16(const void* g, void* l) {
  __builtin_amdgcn_global_load_lds(
      (const __attribute__((address_space(1))) unsigned int*)g,
      (__attribute__((address_space(3))) unsigned int*)l,
      16, 0, 0);
}

DEV unsigned short f2bf(float x) {
  union { float f; unsigned int u; } v; v.f = x;
  unsigned int u = v.u;
  u += 0x7FFFu + ((u >> 16) & 1u);   // round-to-nearest-even
  return (unsigned short)(u >> 16);
}

DEV float bf2f(unsigned short s) {
  union { unsigned int u; float f; } v; v.u = ((unsigned int)s) << 16;
  return v.f;
}

// ---------------------------------------------------------------------------
// Compile-time schedule + slice-count tables.
// R15: K-slices are CHUNK-granular ranges [su, su+cnt) over the cell's
// global (valid-tap, k-chunk) unit stream (1 unit = 32 channels of 1 tap).
// conv1: 288-unit tap-aligned slices (identical to R14).  conv2: balanced
// 172-174-step slices (was 160-192 — critical block -10%).  cnt kept EVEN
// (main loop is 2-step unrolled).
// entry: x2:5 | n:2 | z:3 | su:10 | cnt:10
// ---------------------------------------------------------------------------
struct Sched { unsigned v[256]; int n; };
struct NsTab { unsigned char v[25]; };

constexpr void cell_kdv(bool conv1, int x2, bool kdv[3]) {
  const int m0 = x2 * 256;
  const int cA = m0 / 196;
  int cB = (m0 + 255) / 196; if (cB > 31) cB = 31;
  for (int c = cA; c <= cB; ++c) {
    int t = c >> 2, d = c & 3;
    for (int kd = 0; kd < 3; ++kd) {
      int s = d + kd;
      bool ok = (s >= 1 && s <= 4);
      if (conv1) ok = ok && (s >= 5 - t);
      kdv[kd] = kdv[kd] || ok;
    }
  }
}

constexpr Sched mk_sched(bool conv1) {
  Sched out{};
  const int nt = conv1 ? 4 : 2;
  unsigned L[256] = {};
  int cnt = 0;
  for (int n = 0; n < nt; ++n) {
    for (int x2 = 0; x2 < 25; ++x2) {
      bool kdv[3] = {false, false, false};
      cell_kdv(conv1, x2, kdv);
      int nv = 0;
      for (int tp = 0; tp < 27; ++tp) if (kdv[tp / 9]) ++nv;
      if (!nv) continue;
      const int units = nv * 32;
      const int ns = conv1 ? (nv / 9) : ((nv == 27) ? 5 : 4);
      int bnd[8] = {};
      bnd[0] = 0; bnd[ns] = units;
      for (int s = 1; s < ns; ++s) bnd[s] = ((units * s / ns) + 1) & ~1;
      for (int s = 0; s < ns; ++s) {
        const int su = bnd[s], c = bnd[s + 1] - bnd[s];
        L[cnt++] = (unsigned)(x2 | (n << 5) | (s << 7) | (su << 10) | (c << 20));
      }
    }
  }
  // XCD-grouped interleave: block g -> XCD g%8 contiguous chunk.
  const int q = cnt / 8, r = cnt % 8;
  int pos = 0;
  for (int b = 0; b < 8; ++b) {
    const int nb = q + (b < r ? 1 : 0);
    for (int j = 0; j < nb; ++j) out.v[j * 8 + b] = L[pos++];
  }
  out.n = cnt;
  return out;
}

constexpr NsTab mk_ns(bool conv1) {
  NsTab t{};
  for (int x2 = 0; x2 < 25; ++x2) {
    bool kdv[3] = {false, false, false};
    cell_kdv(conv1, x2, kdv);
    int nv = 0;
    for (int tp = 0; tp < 27; ++tp) if (kdv[tp / 9]) ++nv;
    t.v[x2] = (nv == 0) ? 0 : (unsigned char)(conv1 ? (nv / 9) : ((nv == 27) ? 5 : 4));
  }
  return t;
}

constexpr Sched S1h = mk_sched(true);    // host: grid sizes
constexpr Sched S2h = mk_sched(false);
__constant__ Sched dS1 = mk_sched(true);  // device copies
__constant__ Sched dS2 = mk_sched(false);
__constant__ NsTab dNS1 = mk_ns(true);
__constant__ NsTab dNS2 = mk_ns(false);

// ---------------------------------------------------------------------------
// prep1 = wtrans(conv1_w) U build_P1 — independent, one launch, overlap.
// blocks [0,4096): weight transform; [4096,4224): P1 build.
// ---------------------------------------------------------------------------
__global__ __launch_bounds__(256) void prep1(
    const float* __restrict__ w, unsigned short* __restrict__ wt,
    const float* __restrict__ videos, unsigned short* __restrict__ P1) {
  __shared__ unsigned short l[256 * 27];
  __shared__ unsigned short tile[64][196];
  const int tid = threadIdx.x;
  if (blockIdx.x < 4096) {
    const int base = blockIdx.x * 256;
    #pragma unroll 1
    for (int j = tid; j < 256 * 27; j += 256)
      l[j] = f2bf(w[(size_t)base * 27 + j]);
    __syncthreads();
    #pragma unroll 1
    for (int tap = 0; tap < 27; ++tap)
      wt[(size_t)tap * (1024 * 1024) + base + tid] = l[tid * 27 + tap];
  } else {
    const int idx = blockIdx.x - 4096;
    const int f  = idx >> 4;
    const int c0 = (idx & 15) * 64;
    #pragma unroll 1
    for (int it = 0; it < 49; ++it) {     // 49*256 = 64*196 exactly
      int j = it * 256 + tid;
      int c = j / 196, r = j - c * 196;
      tile[c][r] = f2bf(videos[(size_t)(f * 1024 + c0 + c) * 196 + r]);
    }
    __syncthreads();
    const int c   = tid & 63;
    const int hwq = tid >> 6;
    #pragma unroll 1
    for (int s = 1; s <= 4; ++s) {
      int t = f + 5 - s;
      if (t > 7) continue;
      unsigned short* dst = P1 + (size_t)(t * 6 + s) * 256 * 1024 + (size_t)c0;
      #pragma unroll 1
      for (int it = 0; it < 49; ++it) {
        int hw = it * 4 + hwq;
        int h = hw / 14, w2 = hw - h * 14;
        dst[(size_t)((h + 1) * 16 + (w2 + 1)) * 1024 + c] = tile[c][hw];
      }
    }
  }
}

// ---------------------------------------------------------------------------
// prep2 = wtrans(conv2_w) U reduce_conv1 — independent, one launch.
// blocks [0,2048): W2t; [2048,8320): reduce1 (sum ns slices + bias, relu,
// scatter into padded P2; ns from constexpr table, no part memset needed).
// ---------------------------------------------------------------------------
__global__ __launch_bounds__(256) void prep2(
    const float* __restrict__ w, unsigned short* __restrict__ wt,
    const unsigned short* __restrict__ part, const float* __restrict__ bias,
    unsigned short* __restrict__ P2) {
  __shared__ unsigned short l[256 * 27];
  const int tid = threadIdx.x;
  if (blockIdx.x < 2048) {
    const int base = blockIdx.x * 256;
    #pragma unroll 1
    for (int j = tid; j < 256 * 27; j += 256)
      l[j] = f2bf(w[(size_t)base * 27 + j]);
    __syncthreads();
    #pragma unroll 1
    for (int tap = 0; tap < 27; ++tap)
      wt[(size_t)tap * (512 * 1024) + base + tid] = l[tid * 27 + tap];
  } else {
    const int m  = blockIdx.x - 2048;     // 0..6271
    const int o4 = tid * 4;
    const int ns = dNS1.v[m >> 8];
    const size_t ss = (size_t)M_PAD * 1024;
    const size_t base = (size_t)m * 1024 + o4;
    float v[4];
    #pragma unroll
    for (int k = 0; k < 4; ++k) v[k] = bias[o4 + k];
    #pragma unroll 1
    for (int z = 0; z < ns; ++z) {
      ushort4v p = *(const ushort4v*)(part + (size_t)z * ss + base);
      #pragma unroll
      for (int k = 0; k < 4; ++k) v[k] += bf2f(p[k]);
    }
    ushort4v out;
    #pragma unroll
    for (int k = 0; k < 4; ++k) out[k] = f2bf(v[k] > 0.f ? v[k] : 0.f);
    int t = m / 784;  int r2 = m - t * 784;
    int d = r2 / 196; int r3 = r2 - d * 196;
    int h = r3 / 14;  int w2 = r3 - h * 14;
    size_t didx = (size_t)(((t * 6 + d + 1) * 16 + (h + 1)) * 16 + (w2 + 1)) * 1024 + o4;
    *(ushort4v*)(P2 + didx) = out;
  }
}

// Pinned-order LDS read (issue order = program order among volatile asm).
#define DSR(dst, addr, off) \
  asm volatile("ds_read_b128 %0, %1 offset:" #off : "=&v"(dst) : "v"(addr))
#define WAITL(n) \
  asm volatile("s_waitcnt lgkmcnt(" #n ")" ::: "memory"); \
  __builtin_amdgcn_sched_barrier(0)
#define SB0 __builtin_amdgcn_sched_barrier(0)

// ---------------------------------------------------------------------------
// conv_gemm: R13/R14 pre-read ladder pipeline (validated best), sched now
// chunk-granular (su,cnt).  Structure unchanged:
//  - 4-slot LDS quad buffer, stage t+3 into (t-1)&3, boundary vmcnt(4)
//  - cross-step pre-read of b0..b3,a0,a1 into E/O register banks
//  - counted-lgkm ladder, ONE barrier per step, setprio on MFMA
// ---------------------------------------------------------------------------
template <int COUT, bool TCOND>
__global__ __launch_bounds__(512, 2) void conv_gemm(
    const unsigned short* __restrict__ P,
    const unsigned short* __restrict__ Wt,
    unsigned short* __restrict__ part)
{
  constexpr int CIN = 1024;
  __shared__ short lA[4][8192];   // 4 slots x 16 KiB  (256 rows x 32 k)
  __shared__ short lB[4][8192];
  const int tid  = threadIdx.x;
  const int wave = tid >> 6;
  const int lane = tid & 63;

  const unsigned int e = (TCOND ? dS1 : dS2).v[blockIdx.x];
  const int x2   = e & 31;
  const int nidx = (e >> 5) & 3;
  const int zs   = (e >> 7) & 7;
  const int su   = (e >> 10) & 1023;
  const int steps = (e >> 20) & 1023;     // even, >= 144
  const int m0 = x2 * 256;
  const int n0 = nidx * 256;
  unsigned short* partOut = part + (size_t)zs * M_PAD * COUT;

  // Tile-level depth-tap validity over spanned REAL (t,d) cells (pad excluded).
  bool kdv[3] = {false, false, false};
  {
    const int cA = m0 / 196;
    int cB = (m0 + 255) / 196; if (cB > 31) cB = 31;
    for (int c = cA; c <= cB; ++c) {
      int t = c >> 2, d = c & 3;
      #pragma unroll
      for (int kd = 0; kd < 3; ++kd) {
        int s = d + kd;
        bool ok = (s >= 1) && (s <= 4);
        if (TCOND) ok = ok && (s >= 5 - t);
        kdv[kd] = kdv[kd] || ok;
      }
    }
  }

  // Staging geometry: thread covers (row = tid>>2 within 128-row half,
  // seg = tid&3); global source pre-swizzled: chunk (tid&3) ^ ((row>>1)&3).
  const int arow = tid >> 2;
  const int aswz = (((tid & 3) ^ ((arow >> 1) & 3)) << 4);
  int aG[2], bG[2];
  #pragma unroll
  for (int q = 0; q < 2; ++q) {
    int m = m0 + q * 128 + arow;
    int t = m / 784;  int r2 = m - t * 784;
    int d = r2 / 196; int r3 = r2 - d * 196;
    int h = r3 / 14;  int w = r3 - h * 14;
    aG[q] = ((((t * 6 + d) * 16 + h) * 16 + w) * CIN) * 2 + aswz;
    bG[q] = (n0 + q * 128 + arow) * (CIN * 2) + aswz;
  }

  const char* Pb = (const char*)P;
  const char* Wb = (const char*)Wt;

  // Unit iterator init from su (unit = (valid-tap index)*32 + chunk).
  int tapS = 0;
  {
    int need = su >> 5;
    while (!kdv[tapS / 9]) ++tapS;
    while (need--) { do { ++tapS; } while (!kdv[tapS / 9]); }
  }
  int scnt = su & 31;
  const char *pa0 = nullptr, *pa1 = nullptr, *pb0 = nullptr, *pb1 = nullptr;
  auto tapBase = [&]() {
    const int kd = tapS / 9, rm = tapS - kd * 9;
    const int kh = rm / 3, kw = rm - kh * 3;
    const int tA = ((((kd * 16) + kh) * 16 + kw) * CIN) * 2;
    const int tB = tapS * (COUT * CIN * 2);
    pa0 = Pb + aG[0] + tA;  pa1 = Pb + aG[1] + tA;
    pb0 = Wb + bG[0] + tB;  pb1 = Wb + bG[1] + tB;
  };
  tapBase();
  pa0 += scnt * 64; pa1 += scnt * 64; pb0 += scnt * 64; pb1 += scnt * 64;
  auto advS = [&]() {
    if (++scnt == 32) {
      scnt = 0;
      do { ++tapS; } while (tapS < 27 && !kdv[tapS / 9]);
      if (tapS < 27) tapBase();
    } else {
      pa0 += 64; pa1 += 64; pb0 += 64; pb1 += 64;
    }
  };

  char* lAc = (char*)&lA[0][0];
  char* lBc = (char*)&lB[0][0];
  const unsigned ldsA0 =
      (unsigned)(size_t)(__attribute__((address_space(3))) char*)lAc;
  const unsigned ldsB0 =
      (unsigned)(size_t)(__attribute__((address_space(3))) char*)lBc;

  // Prologue: stage slots 0,1,2 (12 vm loads); vmcnt(4) retires slots 0,1
  // (keeps stage-2 in flight); barrier.
  #pragma unroll 1
  for (int s = 0; s < 3; ++s) {
    char* dA = lAc + s * 16384;
    char* dB = lBc + s * 16384;
    async_ld16(pa0, dA + tid * 16);
    async_ld16(pb0, dB + tid * 16);
    async_ld16(pa1, dA + 8192 + tid * 16);
    async_ld16(pb1, dB + 8192 + tid * 16);
    advS();
  }
  asm volatile("s_waitcnt vmcnt(4)" ::: "memory");
  __builtin_amdgcn_s_barrier();
  SB0;

  const int wm   = (wave >> 2) * 128;
  const int wn   = (wave & 3) * 64;
  const int quad = lane >> 4;
  const int l15  = lane & 15;
  const int segc = ((quad ^ ((l15 >> 1) & 3)) << 4);
  const unsigned rowA = ((unsigned)(wm + l15) << 6) + segc;   // + i*1024 imm
  const unsigned rowB = ((unsigned)(wn + l15) << 6) + segc;   // + j*1024 imm

  floatx4 acc[8][4];
  const floatx4 zero4 = {0.f, 0.f, 0.f, 0.f};
  #pragma unroll
  for (int i = 0; i < 8; ++i)
    #pragma unroll
    for (int j = 0; j < 4; ++j) acc[i][j] = zero4;

  // Pre-read banks (E: even steps, O: odd steps).  Constant indices only.
  int4v pbE0, pbE1, pbE2, pbE3, paE0, paE1;
  int4v pbO0, pbO1, pbO2, pbO3, paO0, paO1;

  // Prologue pre-read for step 0 (slot 0 resident after vmcnt(4)+barrier).
  {
    const unsigned aB = ldsA0 + rowA;
    const unsigned bB = ldsB0 + rowB;
    DSR(pbE0, bB, 0);
    DSR(pbE1, bB, 1024);
    DSR(pbE2, bB, 2048);
    DSR(pbE3, bB, 3072);
    DSR(paE0, aB, 0);
    DSR(paE1, aB, 1024);
  }
  SB0;

#define MFMA_GRP(ACCI, AV)                                                  \
  {                                                                         \
    short8 a_ = __builtin_bit_cast(short8, AV);                             \
    acc[ACCI][0] = __builtin_amdgcn_mfma_f32_16x16x32_bf16(a_, bs0, acc[ACCI][0], 0, 0, 0); \
    acc[ACCI][1] = __builtin_amdgcn_mfma_f32_16x16x32_bf16(a_, bs1, acc[ACCI][1], 0, 0, 0); \
    acc[ACCI][2] = __builtin_amdgcn_mfma_f32_16x16x32_bf16(a_, bs2, acc[ACCI][2], 0, 0, 0); \
    acc[ACCI][3] = __builtin_amdgcn_mfma_f32_16x16x32_bf16(a_, bs3, acc[ACCI][3], 0, 0, 0); \
  }

#define STEP_BODY(U, PB0, PB1, PB2, PB3, PA0, PA1, NB0, NB1, NB2, NB3, NA0, NA1) \
  {                                                                         \
    const int u_ = (U);                                                     \
    const bool h3s = (u_ + 3 < steps);                                      \
    const unsigned aB = ldsA0 + (unsigned)(u_ & 3) * 16384u + rowA;         \
    int4v f2, f3, f4, f5, f6, f7;                                           \
    DSR(f2, aB, 2048);                                                      \
    DSR(f3, aB, 3072);                                                      \
    DSR(f4, aB, 4096);                                                      \
    DSR(f5, aB, 5120);                                                      \
    DSR(f6, aB, 6144);                                                      \
    DSR(f7, aB, 7168);                                                      \
    SB0;                                                                    \
    if (h3s) {                                                              \
      char* dA = lAc + ((u_ + 3) & 3) * 16384;                              \
      char* dB = lBc + ((u_ + 3) & 3) * 16384;                              \
      async_ld16(pa0, dA + tid * 16);                                       \
      async_ld16(pb0, dB + tid * 16);                                       \
      async_ld16(pa1, dA + 8192 + tid * 16);                                \
      async_ld16(pb1, dB + 8192 + tid * 16);                                \
      advS();                                                               \
    }                                                                       \
    SB0;                                                                    \
    __builtin_amdgcn_s_setprio(1);                                          \
    short8 bs0, bs1, bs2, bs3;                                              \
    WAITL(7);                                                               \
    bs0 = __builtin_bit_cast(short8, PB0);                                  \
    bs1 = __builtin_bit_cast(short8, PB1);                                  \
    bs2 = __builtin_bit_cast(short8, PB2);                                  \
    bs3 = __builtin_bit_cast(short8, PB3);                                  \
    MFMA_GRP(0, PA0);                                                       \
    WAITL(6); MFMA_GRP(1, PA1);                                             \
    WAITL(5); MFMA_GRP(2, f2);                                              \
    WAITL(4); MFMA_GRP(3, f3);                                              \
    WAITL(3); MFMA_GRP(4, f4);                                              \
    WAITL(2); MFMA_GRP(5, f5);                                              \
    WAITL(1); MFMA_GRP(6, f6);                                              \
    WAITL(0); MFMA_GRP(7, f7);                                              \
    __builtin_amdgcn_s_setprio(0);                                          \
    SB0;                                                                    \
    if (u_ + 1 < steps) {                                                   \
      const unsigned nA = ldsA0 + (unsigned)((u_ + 1) & 3) * 16384u + rowA; \
      const unsigned nB = ldsB0 + (unsigned)((u_ + 1) & 3) * 16384u + rowB; \
      DSR(NB0, nB, 0);                                                      \
      DSR(NB1, nB, 1024);                                                   \
      DSR(NB2, nB, 2048);                                                   \
      DSR(NB3, nB, 3072);                                                   \
      DSR(NA0, nA, 0);                                                      \
      DSR(NA1, nA, 1024);                                                   \
    }                                                                       \
    SB0;                                                                    \
    if (h3s) { asm volatile("s_waitcnt vmcnt(4)" ::: "memory"); }           \
    else     { asm volatile("s_waitcnt vmcnt(0)" ::: "memory"); }           \
    SB0;                                                                    \
    __builtin_amdgcn_s_barrier();                                           \
    SB0;                                                                    \
  }

  #pragma unroll 1
  for (int t = 0; t < steps; t += 2) {
    STEP_BODY(t,     pbE0, pbE1, pbE2, pbE3, paE0, paE1,
                     pbO0, pbO1, pbO2, pbO3, paO0, paO1);
    STEP_BODY(t + 1, pbO0, pbO1, pbO2, pbO3, paO0, paO1,
                     pbE0, pbE1, pbE2, pbE3, paE0, paE1);
  }

  // Full drain before epilogue (nothing may leak past kernel end).
  asm volatile("s_waitcnt vmcnt(0) lgkmcnt(0)" ::: "memory");
  __builtin_amdgcn_s_barrier();

  // Epilogue: C/D layout col=lane&15, row=quad*4+reg. Raw bf16 partials.
  #pragma unroll
  for (int j = 0; j < 4; ++j) {
    const int o = n0 + wn + j * 16 + l15;
    #pragma unroll
    for (int i = 0; i < 8; ++i) {
      #pragma unroll
      for (int r = 0; r < 4; ++r) {
        int m = m0 + wm + i * 16 + quad * 4 + r;
        partOut[(size_t)m * COUT + o] = f2bf(acc[i][j][r]);
      }
    }
  }
#undef STEP_BODY
#undef MFMA_GRP
}

// ---------------------------------------------------------------------------
// reduce2: sum ns2(x2) bf16 partial slices + bias, relu -> h2 [6272][512].
// ---------------------------------------------------------------------------
__global__ void reduce_conv2(const unsigned short* __restrict__ part,
                             const float* __restrict__ bias,
                             unsigned short* __restrict__ h2) {
  const int idx = blockIdx.x * 256 + threadIdx.x;
  const int m  = idx >> 7;
  const int o4 = (idx & 127) * 4;
  const int ns = dNS2.v[m >> 8];
  const size_t base = (size_t)m * 512 + o4;
  const size_t ss = (size_t)M_PAD * 512;
  float acc[4];
  #pragma unroll
  for (int k = 0; k < 4; ++k) acc[k] = bias[o4 + k];
  #pragma unroll 1
  for (int s = 0; s < ns; ++s) {
    ushort4v p = *(const ushort4v*)(part + (size_t)s * ss + base);
    #pragma unroll
    for (int k = 0; k < 4; ++k) acc[k] += bf2f(p[k]);
  }
  ushort4v out;
  #pragma unroll
  for (int k = 0; k < 4; ++k) out[k] = f2bf(acc[k] > 0.f ? acc[k] : 0.f);
  *(ushort4v*)(h2 + base) = out;
}

// ---------------------------------------------------------------------------
// Max-pool stage 1. h2 bf16 >= 0 -> bit pattern monotone -> max raw ushorts.
// ---------------------------------------------------------------------------
__global__ void pool1(const unsigned short* __restrict__ h2,
                      unsigned short* __restrict__ partial) {
  const int t = blockIdx.x / 28, ch = blockIdx.x % 28, o = threadIdx.x;
  const unsigned short* src = h2 + ((size_t)t * 784 + ch * 28) * 512 + o;
  unsigned short m = 0;
  #pragma unroll 4
  for (int i = 0; i < 28; ++i) { unsigned short v = src[(size_t)i * 512]; m = v > m ? v : m; }
  partial[((size_t)t * 28 + ch) * 512 + o] = m;
}

// ---------------------------------------------------------------------------
// MLP split into 3 wide-grid GEMV kernels (R15): the old single 8-block
// kernel ran on 8 CUs, weight-fetch bound.  Layer1 fuses pool stage 2.
// ---------------------------------------------------------------------------
__global__ __launch_bounds__(128) void mlp_l1(
    const unsigned short* __restrict__ ppart,
    const float* __restrict__ w1, const float* __restrict__ b1,
    float* __restrict__ h1) {
  const int t = blockIdx.x >> 2, jc = blockIdx.x & 3, tid = threadIdx.x;
  __shared__ float xa[512];
  #pragma unroll
  for (int q = 0; q < 4; ++q) {
    const int c = tid * 4 + q;
    const unsigned short* src = ppart + (size_t)t * 28 * 512 + c;
    unsigned short m = 0;
    #pragma unroll 4
    for (int i = 0; i < 28; ++i) { unsigned short v = src[(size_t)i * 512]; m = v > m ? v : m; }
    xa[c] = bf2f(m);
  }
  __syncthreads();
  const int j = jc * 128 + tid;
  const float4* wr = (const float4*)(w1 + (size_t)j * 512);
  float s = b1[j];
  #pragma unroll 4
  for (int k = 0; k < 128; ++k) {
    float4 wv = wr[k];
    s += wv.x * xa[4*k] + wv.y * xa[4*k+1] + wv.z * xa[4*k+2] + wv.w * xa[4*k+3];
  }
  h1[t * 512 + j] = fmaxf(s, 0.f);
}

__global__ __launch_bounds__(128) void mlp_l2(
    const float* __restrict__ h1,
    const float* __restrict__ w2, const float* __restrict__ b2,
    float* __restrict__ h2o) {
  const int t = blockIdx.x >> 2, jc = blockIdx.x & 3, tid = threadIdx.x;
  __shared__ float xa[512];
  #pragma unroll
  for (int q = 0; q < 4; ++q) {
    const int c = tid * 4 + q;
    xa[c] = h1[t * 512 + c];
  }
  __syncthreads();
  const int j = jc * 128 + tid;
  const float4* wr = (const float4*)(w2 + (size_t)j * 512);
  float s = b2[j];
  #pragma unroll 4
  for (int k = 0; k < 128; ++k) {
    float4 wv = wr[k];
    s += wv.x * xa[4*k] + wv.y * xa[4*k+1] + wv.z * xa[4*k+2] + wv.w * xa[4*k+3];
  }
  h2o[t * 512 + j] = fmaxf(s, 0.f);
}

__global__ __launch_bounds__(128) void mlp_l3(
    const float* __restrict__ h2o,
    const float* __restrict__ w3, const float* __restrict__ b3,
    float* __restrict__ out) {
  const int t = blockIdx.x, tid = threadIdx.x;
  __shared__ float xa[512];
  #pragma unroll
  for (int q = 0; q < 4; ++q) {
    const int c = tid * 4 + q;
    xa[c] = h2o[t * 512 + c];
  }
  __syncthreads();
  const float4* wr = (const float4*)(w3 + (size_t)tid * 512);
  float s = b3[tid];
  #pragma unroll 4
  for (int k = 0; k < 128; ++k) {
    float4 wv = wr[k];
    s += wv.x * xa[4*k] + wv.y * xa[4*k+1] + wv.z * xa[4*k+2] + wv.w * xa[4*k+3];
  }
  out[t * 128 + tid] = fmaxf(s, 0.f);
}

// ---------------------------------------------------------------------------
// Workspace layout (bytes) — total 122,683,392:
//   P12 (P1/P2, 51 slots incl t=8 pad) @ 0         : 26,738,688
//   W1t                       @ 26,738,688         : 56,623,104  (dead after gemm1)
//     W2t  (aliases W1t)      @ 26,738,688         : 28,311,552  (built after gemm1)
//     h2                      @ 55,050,240         :  6,422,528
//     ppart                   @ 61,489,152         :    229,376
//     mlpA / mlpB             @ 61,718,528 / 61,734,912 : 16,384 each
//   part                      @ 83,361,792         : 39,321,600
// Dispatches: 1 memset + 9 kernels.
// ---------------------------------------------------------------------------
extern "C" void kernel_launch(void* const* d_in, const int* in_sizes, int n_in,
                              void* d_out, int out_size, void* d_ws, size_t ws_size,
                              hipStream_t stream) {
  const float* videos = (const float*)d_in[0];
  const float* c1w = (const float*)d_in[1];
  const float* c1b = (const float*)d_in[2];
  const float* c2w = (const float*)d_in[3];
  const float* c2b = (const float*)d_in[4];
  const float* l1w = (const float*)d_in[5];
  const float* l1b = (const float*)d_in[6];
  const float* l2w = (const float*)d_in[7];
  const float* l2b = (const float*)d_in[8];
  const float* l3w = (const float*)d_in[9];
  const float* l3b = (const float*)d_in[10];

  char* ws = (char*)d_ws;
  unsigned short* P12   = (unsigned short*)(ws);
  unsigned short* W1t   = (unsigned short*)(ws + 26738688);
  unsigned short* W2t   = (unsigned short*)(ws + 26738688);   // aliases W1t
  unsigned short* h2    = (unsigned short*)(ws + 55050240);
  unsigned short* ppart = (unsigned short*)(ws + 61489152);
  float*          mlpA  = (float*)(ws + 61718528);
  float*          mlpB  = (float*)(ws + 61734912);
  unsigned short* part  = (unsigned short*)(ws + 83361792);
  float* out = (float*)d_out;

  // Zero padded activation buffer (halo + unused windows + t=8 pad slots).
  hipMemsetAsync(ws, 0, 26738688, stream);

  prep1<<<4224, 256, 0, stream>>>(c1w, W1t, videos, P12);
  conv_gemm<1024, true ><<<S1h.n, 512, 0, stream>>>(P12, W1t, part);

  // prep2: W2t overwrites W1t (dead after gemm1) + reduce1 -> P2.
  prep2<<<8320, 256, 0, stream>>>(c2w, W2t, part, c1b, P12);

  conv_gemm<512, false><<<S2h.n, 512, 0, stream>>>(P12, W2t, part);
  reduce_conv2<<<3136, 256, 0, stream>>>(part, c2b, h2);

  pool1<<<224, 512, 0, stream>>>(h2, ppart);
  mlp_l1<<<32, 128, 0, stream>>>(ppart, l1w, l1b, mlpA);
  mlp_l2<<<32, 128, 0, stream>>>(mlpA, l2w, l2b, mlpB);
  mlp_l3<<<8, 128, 0, stream>>>(mlpB, l3w, l3b, out);
}